// Round 5
// baseline (471.467 us; speedup 1.0000x reference)
//
#include <hip/hip_runtime.h>
#include <hip/hip_bf16.h>
#include <math.h>

#define N_NODES 25000
#define N_EDGES 400000
#define NFEAT   256
#define NHID    32
#define NHEAD   12
#define HC      384
#define NEG_SLOPE 0.2f
#define NBLK    ((N_NODES + 255) / 256)
#define BPAD    40   // LDS row pitch for B-tile (2-way bank aliasing only)
#define NPB     42   // agg1: nodes per block (42*6=252 active threads)

typedef __attribute__((ext_vector_type(8))) short short8;
typedef __attribute__((ext_vector_type(4))) float floatx4;

__device__ __forceinline__ float bf2f(unsigned short u) {
    union { unsigned int i; float f; } v; v.i = ((unsigned int)u) << 16; return v.f;
}
__device__ __forceinline__ unsigned short f2bf(float f) {
    union { float f; unsigned int i; } v; v.f = f;
    unsigned int x = v.i;
    unsigned int r = (x + 0x7FFFu + ((x >> 16) & 1u)) >> 16;
    return (unsigned short)r;
}
__device__ __forceinline__ int clampN(int s) {
    return ((unsigned)s < (unsigned)N_NODES) ? s : 0;
}
__device__ __forceinline__ float ldf(const void* p, size_t i, int isF32) {
    return isF32 ? ((const float*)p)[i] : bf2f(((const unsigned short*)p)[i]);
}
__device__ __forceinline__ int ldi(const void* p, size_t i, int isI64) {
    return isI64 ? (int)((const unsigned int*)p)[2 * i] : ((const int*)p)[i];
}

// 8 bf16 (one uint4) FMA into acc[8]; unpack via bit-ops (lo: u<<16, hi: u&0xFFFF0000)
__device__ __forceinline__ void fma8(float* acc, float a, uint4 g) {
    unsigned int u[4] = {g.x, g.y, g.z, g.w};
#pragma unroll
    for (int i = 0; i < 4; i++) {
        union { unsigned int i; float f; } lo, hi;
        lo.i = u[i] << 16;
        hi.i = u[i] & 0xFFFF0000u;
        acc[2 * i]     += a * lo.f;
        acc[2 * i + 1] += a * hi.f;
    }
}
__device__ __forceinline__ void mul8(float* acc, float a, uint4 g) {
    unsigned int u[4] = {g.x, g.y, g.z, g.w};
#pragma unroll
    for (int i = 0; i < 4; i++) {
        union { unsigned int i; float f; } lo, hi;
        lo.i = u[i] << 16;
        hi.i = u[i] & 0xFFFF0000u;
        acc[2 * i]     = a * lo.f;
        acc[2 * i + 1] = a * hi.f;
    }
}

// ---------------- dtype detection (1 block) ----------------
__global__ void detect_kernel(const unsigned short* __restrict__ xr,
                              const unsigned int* __restrict__ eir,
                              int* __restrict__ flags) {
    __shared__ int sF, sI;
    if (threadIdx.x == 0) { sF = 0; sI = 0; }
    __syncthreads();
    int t = threadIdx.x;
    int cf = 0, ci = 0;
#pragma unroll
    for (int i = 0; i < 4; i++) {
        unsigned short u = xr[2 * (t * 4 + i)];
        int e = (u >> 7) & 0xFF;
        if (e >= 100 && e <= 140) cf++;
        unsigned int v = eir[2 * (t * 4 + i) + 1];
        if (v == 0u) ci++;
    }
    atomicAdd(&sF, cf);
    atomicAdd(&sI, ci);
    __syncthreads();
    if (threadIdx.x == 0) {
        flags[0] = (sF >= 614) ? 0 : 1;   // 1 -> float inputs are f32
        flags[1] = (sI >= 512) ? 1 : 0;   // 1 -> edge_index is i64
    }
}

// ---------------- prep: M1 fold + W1/W2 transpose to bf16 ----------------
__global__ void prep_kernel(const void* __restrict__ We1,
                            const void* __restrict__ att_e,
                            const void* __restrict__ W1,
                            const void* __restrict__ W2,
                            const int* __restrict__ flags,
                            float* __restrict__ M1,
                            unsigned short* __restrict__ Wt1,
                            unsigned short* __restrict__ Wt2) {
    int isF32 = flags[0];
    int id = blockIdx.x * 256 + threadIdx.x;
    if (id < 384) {
        int k = id / 12, h = id % 12;
        float s = 0.f;
        for (int c = 0; c < 32; c++)
            s += ldf(We1, (size_t)k * HC + h * 32 + c, isF32) *
                 ldf(att_e, (size_t)h * 32 + c, isF32);
        M1[k * 12 + h] = s;
        return;
    }
    int id1 = id - 384;
    if (id1 < 384 * 256) {
        int n = id1 / 256, k = id1 % 256;
        Wt1[(size_t)n * 256 + k] = f2bf(ldf(W1, (size_t)k * HC + n, isF32));
        return;
    }
    int id2 = id1 - 384 * 256;
    if (id2 < 384 * 384) {
        int n = id2 / 384, k = id2 % 384;
        Wt2[(size_t)n * 384 + k] = f2bf(ldf(W2, (size_t)k * HC + n, isF32));
    }
}

// ---------------- CSR build ----------------
__global__ void hist_kernel(const void* __restrict__ ei, const int* __restrict__ flags,
                            int* __restrict__ cnt) {
    int isI64 = flags[1];
    int e = blockIdx.x * 256 + threadIdx.x;
    if (e < N_EDGES) {
        int d = clampN(ldi(ei, (size_t)N_EDGES + e, isI64));
        atomicAdd(&cnt[d], 1);
    }
}

// 3-phase device-wide scan
__global__ void blockscan_kernel(const int* __restrict__ cnt, int* __restrict__ incl,
                                 int* __restrict__ bsum) {
    __shared__ int buf[256];
    int i = blockIdx.x * 256 + threadIdx.x;
    int v = (i < N_NODES) ? cnt[i] : 0;
    buf[threadIdx.x] = v;
    __syncthreads();
    for (int off = 1; off < 256; off <<= 1) {
        int t = (threadIdx.x >= off) ? buf[threadIdx.x - off] : 0;
        __syncthreads();
        buf[threadIdx.x] += t;
        __syncthreads();
    }
    if (i < N_NODES) incl[i] = buf[threadIdx.x];
    if (threadIdx.x == 255) bsum[blockIdx.x] = buf[255];
}

__global__ void bscan_kernel(const int* __restrict__ bsum, int* __restrict__ boff) {
    __shared__ int buf[128];
    int t = threadIdx.x;
    int v = (t < NBLK) ? bsum[t] : 0;
    buf[t] = v;
    __syncthreads();
    for (int off = 1; off < 128; off <<= 1) {
        int u = (t >= off) ? buf[t - off] : 0;
        __syncthreads();
        buf[t] += u;
        __syncthreads();
    }
    if (t < NBLK) boff[t] = buf[t] - v;
}

__global__ void finalize_kernel(const int* __restrict__ incl, const int* __restrict__ boff,
                                const int* __restrict__ cnt,
                                int* __restrict__ rowptr, int* __restrict__ wofs) {
    int i = blockIdx.x * 256 + threadIdx.x;
    if (i == 0) rowptr[0] = 0;
    if (i < N_NODES) {
        int v = incl[i] + boff[blockIdx.x];
        rowptr[i + 1] = v;
        wofs[i] = v - cnt[i];
    }
}

// minimal scatter: 8 bytes per edge (src, edge_id)
__global__ void scatter_kernel(const void* __restrict__ ei, const int* __restrict__ flags,
                               int* __restrict__ wofs, int2* __restrict__ pairs) {
    int isI64 = flags[1];
    int e = blockIdx.x * 256 + threadIdx.x;
    if (e >= N_EDGES) return;
    int d = clampN(ldi(ei, (size_t)N_EDGES + e, isI64));
    int pos = atomicAdd(&wofs[d], 1);
    if ((unsigned)pos >= (unsigned)N_EDGES) return;
    pairs[pos] = make_int2(clampN(ldi(ei, (size_t)e, isI64)), e);
}

// folded edge attention in coalesced edge order
__global__ void ae_kernel(const void* __restrict__ ea, const int* __restrict__ flags,
                          const float* __restrict__ M1,
                          unsigned short* __restrict__ ae_edge) {
    __shared__ float sM[384];
    for (int i = threadIdx.x; i < 384; i += 256) sM[i] = M1[i];
    __syncthreads();
    int isF32 = flags[0];
    int e = blockIdx.x * 256 + threadIdx.x;
    if (e >= N_EDGES) return;
    float a[32];
    if (isF32) {
        const float4* r4 = (const float4*)((const float*)ea + (size_t)e * 32);
#pragma unroll
        for (int i = 0; i < 8; i++) {
            float4 v = r4[i];
            a[4 * i] = v.x; a[4 * i + 1] = v.y; a[4 * i + 2] = v.z; a[4 * i + 3] = v.w;
        }
    } else {
        const unsigned short* r = (const unsigned short*)ea + (size_t)e * 32;
#pragma unroll
        for (int i = 0; i < 32; i++) a[i] = bf2f(r[i]);
    }
    float ev[12];
#pragma unroll
    for (int h = 0; h < 12; h++) ev[h] = 0.f;
#pragma unroll
    for (int k = 0; k < 32; k++)
#pragma unroll
        for (int h = 0; h < 12; h++) ev[h] += a[k] * sM[k * 12 + h];
    unsigned int w[6];
#pragma unroll
    for (int i = 0; i < 6; i++)
        w[i] = (unsigned int)f2bf(ev[2 * i]) | ((unsigned int)f2bf(ev[2 * i + 1]) << 16);
    uint2* dst = (uint2*)(ae_edge + (size_t)e * 12);
    dst[0] = make_uint2(w[0], w[1]);
    dst[1] = make_uint2(w[2], w[3]);
    dst[2] = make_uint2(w[4], w[5]);
}

// ---------------- full-N MFMA GEMM ----------------
// v2: 512-thread blocks, 8 waves; wave = 16 rows x 192 cols (12 accs).
__global__ __launch_bounds__(512) void gemm_mfma(const void* __restrict__ A,
                                                 const unsigned short* __restrict__ Bt,
                                                 const int* __restrict__ flags,
                                                 int aFromFlag,
                                                 unsigned short* __restrict__ C,
                                                 int M, int K) {
    __shared__ unsigned short sB[384 * BPAD];   // 30720 B
    int aF32 = aFromFlag ? flags[0] : 0;
    int lane = threadIdx.x & 63;
    int w = threadIdx.x >> 6;            // 0..7
    int m0 = blockIdx.x * 64 + (w >> 1) * 16;
    int c0 = (w & 1) * 192;
    int r = lane & 15, q = lane >> 4;
    int row = m0 + r;
    if (row >= M) row = M - 1;
    floatx4 acc[12];
#pragma unroll
    for (int j = 0; j < 12; j++) acc[j] = (floatx4){0.f, 0.f, 0.f, 0.f};
    for (int k0 = 0; k0 < K; k0 += 32) {
        for (int i = threadIdx.x; i < 384 * 4; i += 512) {
            int col = i >> 2, seg = i & 3;
            *(uint4*)(sB + (size_t)col * BPAD + seg * 8) =
                *(const uint4*)(Bt + (size_t)col * K + k0 + seg * 8);
        }
        __syncthreads();
        short8 a;
        if (aF32) {
            const float4* ap = (const float4*)((const float*)A + (size_t)row * K + k0 + q * 8);
            float4 u = ap[0], v = ap[1];
            a[0] = (short)f2bf(u.x); a[1] = (short)f2bf(u.y);
            a[2] = (short)f2bf(u.z); a[3] = (short)f2bf(u.w);
            a[4] = (short)f2bf(v.x); a[5] = (short)f2bf(v.y);
            a[6] = (short)f2bf(v.z); a[7] = (short)f2bf(v.w);
        } else {
            a = *(const short8*)((const unsigned short*)A + (size_t)row * K + k0 + q * 8);
        }
#pragma unroll
        for (int j = 0; j < 12; j++) {
            int col = c0 + 16 * j + r;
            short8 b = *(const short8*)(sB + (size_t)col * BPAD + q * 8);
            acc[j] = __builtin_amdgcn_mfma_f32_16x16x32_bf16(a, b, acc[j], 0, 0, 0);
        }
        __syncthreads();
    }
#pragma unroll
    for (int j = 0; j < 12; j++) {
        int col = c0 + 16 * j + r;
#pragma unroll
        for (int t = 0; t < 4; t++) {
            int orow = m0 + q * 4 + t;
            if (orow < M) C[(size_t)orow * HC + col] = f2bf(acc[j][t]);
        }
    }
}

// ---------------- per-(node,head) attention logits ----------------
__global__ __launch_bounds__(256) void att_kernel(const unsigned short* __restrict__ hx,
                           const void* __restrict__ att_src,
                           const void* __restrict__ att_dst,
                           const int* __restrict__ flags,
                           float* __restrict__ a_s, float* __restrict__ a_d) {
    __shared__ float sS[12 * 33];
    __shared__ float sD[12 * 33];
    int isF32 = flags[0];
    for (int i = threadIdx.x; i < 384; i += 256) {
        int hh = i >> 5, c = i & 31;
        sS[hh * 33 + c] = ldf(att_src, (size_t)i, isF32);
        sD[hh * 33 + c] = ldf(att_dst, (size_t)i, isF32);
    }
    __syncthreads();
    int id = blockIdx.x * 256 + threadIdx.x;
    if (id >= N_NODES * NHEAD) return;
    int n = id / NHEAD;
    int h = id - n * NHEAD;
    const short8* row = (const short8*)(hx + (size_t)n * HC + h * 32);
    float s = 0.f, d = 0.f;
#pragma unroll
    for (int i = 0; i < 4; i++) {
        short8 v = row[i];
#pragma unroll
        for (int j = 0; j < 8; j++) {
            float f = bf2f((unsigned short)v[j]);
            int c = i * 8 + j;
            s += f * sS[h * 33 + c];
            d += f * sD[h * 33 + c];
        }
    }
    a_s[id] = s;
    a_d[id] = d;
}

// ---------------- segment softmax: thread = (node, head) ----------------
__global__ __launch_bounds__(256) void softmax_kernel(const float* __restrict__ a_s,
                                                      const float* __restrict__ a_d,
                                                      const int* __restrict__ rowptr,
                                                      const int2* __restrict__ pairs,
                                                      const unsigned short* __restrict__ ae_edge,
                                                      unsigned short* __restrict__ alpha_e,
                                                      float* __restrict__ exl_out,
                                                      float* __restrict__ rden_out,
                                                      int has_ae) {
    int id = blockIdx.x * 256 + threadIdx.x;
    if (id >= N_NODES * NHEAD) return;
    int node = id / NHEAD;
    int h = id - node * NHEAD;
    int start = rowptr[node], end = rowptr[node + 1];
    if (start < 0) start = 0;
    if (end > N_EDGES) end = N_EDGES;
    int deg = end - start;
    float adn = a_d[id];
    float asn = a_s[id];
    float mx = -1e30f, sae = 0.f;
    // pass 1: segment max + edge-attn sum
    for (int p = start; p < end; p += 2) {
        int2 pe0 = pairs[p];
        bool two = (p + 1 < end);
        int2 pe1 = two ? pairs[p + 1] : pe0;
        int s0 = clampN(pe0.x), s1 = clampN(pe1.x);
        float v0 = a_s[(size_t)s0 * NHEAD + h] + adn;
        float v1 = a_s[(size_t)s1 * NHEAD + h] + adn;
        if (has_ae) {
            int e0 = ((unsigned)pe0.y < (unsigned)N_EDGES) ? pe0.y : 0;
            int e1 = ((unsigned)pe1.y < (unsigned)N_EDGES) ? pe1.y : 0;
            float a0 = bf2f(ae_edge[(size_t)e0 * NHEAD + h]);
            float a1 = bf2f(ae_edge[(size_t)e1 * NHEAD + h]);
            v0 += a0; sae += a0;
            if (two) { v1 += a1; sae += a1; }
        }
        v0 = v0 > 0.f ? v0 : NEG_SLOPE * v0;
        v1 = v1 > 0.f ? v1 : NEG_SLOPE * v1;
        mx = fmaxf(mx, v0);
        if (two) mx = fmaxf(mx, v1);
    }
    float invdeg = 1.f / fmaxf((float)deg, 1.f);
    float el = asn + adn + (has_ae ? sae * invdeg : 0.f);
    el = el > 0.f ? el : NEG_SLOPE * el;
    mx = fmaxf(mx, el);
    // pass 2: recompute v (f32-exact), exp, store unnormalized alpha, denom
    float den = 0.f;
    for (int p = start; p < end; p += 2) {
        int2 pe0 = pairs[p];
        bool two = (p + 1 < end);
        int2 pe1 = two ? pairs[p + 1] : pe0;
        int s0 = clampN(pe0.x), s1 = clampN(pe1.x);
        float v0 = a_s[(size_t)s0 * NHEAD + h] + adn;
        float v1 = a_s[(size_t)s1 * NHEAD + h] + adn;
        if (has_ae) {
            int e0 = ((unsigned)pe0.y < (unsigned)N_EDGES) ? pe0.y : 0;
            int e1 = ((unsigned)pe1.y < (unsigned)N_EDGES) ? pe1.y : 0;
            v0 += bf2f(ae_edge[(size_t)e0 * NHEAD + h]);
            v1 += bf2f(ae_edge[(size_t)e1 * NHEAD + h]);
        }
        v0 = v0 > 0.f ? v0 : NEG_SLOPE * v0;
        v1 = v1 > 0.f ? v1 : NEG_SLOPE * v1;
        float ex0 = expf(v0 - mx);
        float ex1 = expf(v1 - mx);
        alpha_e[(size_t)p * NHEAD + h] = f2bf(ex0);
        den += ex0;
        if (two) {
            alpha_e[(size_t)(p + 1) * NHEAD + h] = f2bf(ex1);
            den += ex1;
        }
    }
    float exl = expf(el - mx);
    exl_out[id] = exl;
    rden_out[id] = 1.f / (den + exl);
}

// ---------------- layer-1 aggregation: XCD channel-slice version ----------------
// group = blockIdx & 7 -> one of 8 channel groups (48 ch). With round-robin
// block->XCD mapping, each XCD touches only its 2.4 MB hx slice -> L2-resident
// gathers instead of 141 MB of per-XCD compulsory streaming.
// Thread = (node, 8 channels): 6 threads/node, 42 nodes/block (252 active).
// Per edge: 1 uint4 gather + 1 alpha ushort; 6 adjacent lanes read 96 B
// contiguous. Accumulation order = p ascending (bitwise-identical h1).
__global__ __launch_bounds__(256) void agg1_kernel(const unsigned short* __restrict__ hx,
                                                   const unsigned short* __restrict__ alpha_e,
                                                   const float* __restrict__ exl,
                                                   const float* __restrict__ rden,
                                                   const int* __restrict__ rowptr,
                                                   const int2* __restrict__ pairs,
                                                   const void* __restrict__ b1,
                                                   const int* __restrict__ flags,
                                                   unsigned short* __restrict__ h1) {
    int isF32 = flags[0];
    int t = threadIdx.x;
    if (t >= NPB * 6) return;
    int gq = blockIdx.x & 7;
    int nb = blockIdx.x >> 3;
    int nl = t / 6;
    int node = nb * NPB + nl;
    if (node >= N_NODES) return;
    int cs = t - nl * 6;
    int cidx = 6 * gq + cs;   // 0..47
    int off = cidx * 8;       // channel base
    int h = cidx >> 2;        // head 0..11
    int start = rowptr[node], end = rowptr[node + 1];
    if (start < 0) start = 0;
    if (end > N_EDGES) end = N_EDGES;
    float acc[8];
    {
        uint4 g = *(const uint4*)(hx + (size_t)node * HC + off);
        mul8(acc, exl[node * 12 + h], g);
    }
    int p = start;
    for (; p + 2 <= end; p += 2) {
        int2 pe0 = pairs[p];
        int2 pe1 = pairs[p + 1];
        uint4 g0 = *(const uint4*)(hx + (size_t)clampN(pe0.x) * HC + off);
        uint4 g1 = *(const uint4*)(hx + (size_t)clampN(pe1.x) * HC + off);
        float a0 = bf2f(alpha_e[(size_t)p * 12 + h]);
        float a1 = bf2f(alpha_e[(size_t)(p + 1) * 12 + h]);
        fma8(acc, a0, g0);
        fma8(acc, a1, g1);
    }
    if (p < end) {
        int2 pe = pairs[p];
        uint4 g = *(const uint4*)(hx + (size_t)clampN(pe.x) * HC + off);
        fma8(acc, bf2f(alpha_e[(size_t)p * 12 + h]), g);
    }
    float rd = rden[node * 12 + h];
    unsigned int w[4];
#pragma unroll
    for (int i = 0; i < 4; i++) {
        float v0 = acc[2 * i] * rd + ldf(b1, (size_t)(off + 2 * i), isF32);
        float v1 = acc[2 * i + 1] * rd + ldf(b1, (size_t)(off + 2 * i + 1), isF32);
        v0 = v0 > 0.f ? v0 : expm1f(v0);
        v1 = v1 > 0.f ? v1 : expm1f(v1);
        w[i] = (unsigned int)f2bf(v0) | ((unsigned int)f2bf(v1) << 16);
    }
    *(uint4*)(h1 + (size_t)node * HC + off) = make_uint4(w[0], w[1], w[2], w[3]);
}

// ---------------- layer-2 aggregation + head-mean + bias + log_softmax ----------------
// Round-4 proven structure (48-lane node-wave + pairs software pipeline).
__global__ __launch_bounds__(256) void agg2_kernel(const unsigned short* __restrict__ hx,
                                                   const unsigned short* __restrict__ alpha_e,
                                                   const float* __restrict__ exl,
                                                   const float* __restrict__ rden,
                                                   const int* __restrict__ rowptr,
                                                   const int2* __restrict__ pairs,
                                                   const void* __restrict__ b2,
                                                   const int* __restrict__ flags,
                                                   float* __restrict__ out) {
    int isF32 = flags[0];
    int lane = threadIdx.x & 63;
    int node = blockIdx.x * 4 + (threadIdx.x >> 6);
    if (node >= N_NODES) return;
    bool act = lane < 48;
    int h = act ? (lane >> 2) : 0;
    int off = act ? lane * 8 : 0;
    float acc[8];
#pragma unroll
    for (int k = 0; k < 8; k++) acc[k] = 0.f;
    if (act) {
        int start = rowptr[node], end = rowptr[node + 1];
        if (start < 0) start = 0;
        if (end > N_EDGES) end = N_EDGES;
        {
            uint4 g = *(const uint4*)(hx + (size_t)node * HC + off);
            mul8(acc, exl[node * 12 + h], g);
        }
        int p = start;
        int2 pe0, pe1, pe2, pe3;
        bool have = (p + 4 <= end);
        if (have) {
            pe0 = pairs[p]; pe1 = pairs[p + 1]; pe2 = pairs[p + 2]; pe3 = pairs[p + 3];
        }
        while (have) {
            int2 c0 = pe0, c1 = pe1, c2 = pe2, c3 = pe3;
            bool nxt = (p + 8 <= end);
            if (nxt) {
                pe0 = pairs[p + 4]; pe1 = pairs[p + 5]; pe2 = pairs[p + 6]; pe3 = pairs[p + 7];
            }
            uint4 g0 = *(const uint4*)(hx + (size_t)clampN(c0.x) * HC + off);
            uint4 g1 = *(const uint4*)(hx + (size_t)clampN(c1.x) * HC + off);
            uint4 g2 = *(const uint4*)(hx + (size_t)clampN(c2.x) * HC + off);
            uint4 g3 = *(const uint4*)(hx + (size_t)clampN(c3.x) * HC + off);
            float a0 = bf2f(alpha_e[(size_t)p * 12 + h]);
            float a1 = bf2f(alpha_e[(size_t)(p + 1) * 12 + h]);
            float a2 = bf2f(alpha_e[(size_t)(p + 2) * 12 + h]);
            float a3 = bf2f(alpha_e[(size_t)(p + 3) * 12 + h]);
            fma8(acc, a0, g0);
            fma8(acc, a1, g1);
            fma8(acc, a2, g2);
            fma8(acc, a3, g3);
            p += 4;
            have = nxt;
        }
        for (; p < end; p++) {
            int2 pe = pairs[p];
            uint4 g = *(const uint4*)(hx + (size_t)clampN(pe.x) * HC + off);
            float a = bf2f(alpha_e[(size_t)p * 12 + h]);
            fma8(acc, a, g);
        }
        float rd = rden[node * 12 + h];
#pragma unroll
        for (int k = 0; k < 8; k++) acc[k] *= rd;
    }
    // reduce over 12 heads: lanes {L, L+16, L+32} then butterfly over h bits
#pragma unroll
    for (int k = 0; k < 8; k++) {
        float t1 = __shfl(acc[k], lane + 16);
        float t2 = __shfl(acc[k], lane + 32);
        acc[k] += t1 + t2;
        acc[k] += __shfl_xor(acc[k], 4);
        acc[k] += __shfl_xor(acc[k], 8);
    }
    if (lane < 4) {
        int q = lane;
        float hv[8];
        float m = -1e30f;
#pragma unroll
        for (int t = 0; t < 8; t++) {
            hv[t] = acc[t] * (1.f / 12.f) + ldf(b2, (size_t)(8 * q + t), isF32);
            m = fmaxf(m, hv[t]);
        }
        m = fmaxf(m, __shfl_xor(m, 1));
        m = fmaxf(m, __shfl_xor(m, 2));
        float s = 0.f;
#pragma unroll
        for (int t = 0; t < 8; t++) s += expf(hv[t] - m);
        s += __shfl_xor(s, 1);
        s += __shfl_xor(s, 2);
        float ls = m + logf(s);
        float4* o0 = (float4*)(out + (size_t)node * 32 + 8 * q);
        float4* l0 = (float4*)(out + (size_t)N_NODES * 32 + (size_t)node * 32 + 8 * q);
        o0[0] = make_float4(hv[0], hv[1], hv[2], hv[3]);
        o0[1] = make_float4(hv[4], hv[5], hv[6], hv[7]);
        l0[0] = make_float4(hv[0] - ls, hv[1] - ls, hv[2] - ls, hv[3] - ls);
        l0[1] = make_float4(hv[4] - ls, hv[5] - ls, hv[6] - ls, hv[7] - ls);
    }
}

extern "C" void kernel_launch(void* const* d_in, const int* in_sizes, int n_in,
                              void* d_out, int out_size, void* d_ws, size_t ws_size,
                              hipStream_t stream) {
    const void* x        = d_in[0];
    const void* ei       = d_in[1];
    const void* ea       = d_in[2];
    const void* W1       = d_in[3];
    const void* att_src1 = d_in[4];
    const void* att_dst1 = d_in[5];
    const void* We1      = d_in[6];
    const void* att_e1   = d_in[7];
    const void* b1       = d_in[8];
    const void* W2       = d_in[9];
    const void* att_src2 = d_in[10];
    const void* att_dst2 = d_in[11];
    const void* b2       = d_in[12];
    float* out = (float*)d_out;

    char* ws = (char*)d_ws;
    size_t off = 0;
    auto alloc = [&](size_t bytes) -> void* {
        void* p = ws + off;
        off = (off + bytes + 255) & ~(size_t)255;
        return p;
    };
    int*            flags   = (int*)alloc(16);
    float*          M1      = (float*)alloc((size_t)384 * 4);
    int*            rowptr  = (int*)alloc((size_t)(N_NODES + 1) * 4);
    int*            cnt     = (int*)alloc((size_t)N_NODES * 4);
    int*            wofs    = (int*)alloc((size_t)N_NODES * 4);
    int*            incl    = (int*)alloc((size_t)N_NODES * 4);
    int*            bsum    = (int*)alloc((size_t)NBLK * 4);
    int*            boff    = (int*)alloc((size_t)NBLK * 4);
    float*          a_s     = (float*)alloc((size_t)N_NODES * 12 * 4);
    float*          a_d     = (float*)alloc((size_t)N_NODES * 12 * 4);
    float*          exl     = (float*)alloc((size_t)N_NODES * 12 * 4);
    float*          rden    = (float*)alloc((size_t)N_NODES * 12 * 4);
    int2*           pairs   = (int2*)alloc((size_t)N_EDGES * 8);
    unsigned short* alpha_e = (unsigned short*)alloc((size_t)N_EDGES * 12 * 2);
    unsigned short* hx      = (unsigned short*)alloc((size_t)N_NODES * HC * 2);
    // h1 aliases ae_edge: ae_edge dead after softmax1, h1 born in agg1 (after).
    unsigned short* h1      = (unsigned short*)alloc((size_t)N_NODES * HC * 2);
    unsigned short* ae_edge = h1;
    unsigned short* Wt1     = (unsigned short*)alloc((size_t)384 * 256 * 2);
    unsigned short* Wt2     = (unsigned short*)alloc((size_t)384 * 384 * 2);

    hipMemsetAsync(cnt, 0, (size_t)N_NODES * 4, stream);
    detect_kernel<<<1, 256, 0, stream>>>((const unsigned short*)x, (const unsigned int*)ei, flags);
    prep_kernel<<<(384 + 384 * 256 + 384 * 384 + 255) / 256, 256, 0, stream>>>(
        We1, att_e1, W1, W2, flags, M1, Wt1, Wt2);
    hist_kernel<<<(N_EDGES + 255) / 256, 256, 0, stream>>>(ei, flags, cnt);
    blockscan_kernel<<<NBLK, 256, 0, stream>>>(cnt, incl, bsum);
    bscan_kernel<<<1, 128, 0, stream>>>(bsum, boff);
    finalize_kernel<<<NBLK, 256, 0, stream>>>(incl, boff, cnt, rowptr, wofs);
    scatter_kernel<<<(N_EDGES + 255) / 256, 256, 0, stream>>>(ei, flags, wofs, pairs);
    ae_kernel<<<(N_EDGES + 255) / 256, 256, 0, stream>>>(ea, flags, M1, ae_edge);
    // layer 1
    gemm_mfma<<<(N_NODES + 63) / 64, 512, 0, stream>>>(x, Wt1, flags, 1, hx, N_NODES, NFEAT);
    att_kernel<<<(N_NODES * 12 + 255) / 256, 256, 0, stream>>>(hx, att_src1, att_dst1, flags,
                                                               a_s, a_d);
    softmax_kernel<<<(N_NODES * 12 + 255) / 256, 256, 0, stream>>>(a_s, a_d, rowptr, pairs,
                                                                   ae_edge, alpha_e, exl, rden, 1);
    agg1_kernel<<<((N_NODES + NPB - 1) / NPB) * 8, 256, 0, stream>>>(hx, alpha_e, exl, rden,
                                                                     rowptr, pairs, b1, flags, h1);
    // layer 2
    gemm_mfma<<<(N_NODES + 63) / 64, 512, 0, stream>>>(h1, Wt2, flags, 0, hx, N_NODES, HC);
    att_kernel<<<(N_NODES * 12 + 255) / 256, 256, 0, stream>>>(hx, att_src2, att_dst2, flags,
                                                               a_s, a_d);
    softmax_kernel<<<(N_NODES * 12 + 255) / 256, 256, 0, stream>>>(a_s, a_d, rowptr, pairs,
                                                                   ae_edge, alpha_e, exl, rden, 0);
    agg2_kernel<<<(N_NODES + 3) / 4, 256, 0, stream>>>(hx, alpha_e, exl, rden, rowptr, pairs,
                                                       b2, flags, out);
}

// Round 6
// 427.533 us; speedup vs baseline: 1.1028x; 1.1028x over previous
//
#include <hip/hip_runtime.h>
#include <hip/hip_bf16.h>
#include <math.h>

#define N_NODES 25000
#define N_EDGES 400000
#define NFEAT   256
#define NHID    32
#define NHEAD   12
#define HC      384
#define NEG_SLOPE 0.2f
#define NBLK    ((N_NODES + 255) / 256)
#define BPAD    40   // LDS row pitch for B-tile (2-way bank aliasing only)

typedef __attribute__((ext_vector_type(8))) short short8;
typedef __attribute__((ext_vector_type(4))) float floatx4;

__device__ __forceinline__ float bf2f(unsigned short u) {
    union { unsigned int i; float f; } v; v.i = ((unsigned int)u) << 16; return v.f;
}
__device__ __forceinline__ unsigned short f2bf(float f) {
    union { float f; unsigned int i; } v; v.f = f;
    unsigned int x = v.i;
    unsigned int r = (x + 0x7FFFu + ((x >> 16) & 1u)) >> 16;
    return (unsigned short)r;
}
__device__ __forceinline__ int clampN(int s) {
    return ((unsigned)s < (unsigned)N_NODES) ? s : 0;
}
__device__ __forceinline__ float ldf(const void* p, size_t i, int isF32) {
    return isF32 ? ((const float*)p)[i] : bf2f(((const unsigned short*)p)[i]);
}
__device__ __forceinline__ int ldi(const void* p, size_t i, int isI64) {
    return isI64 ? (int)((const unsigned int*)p)[2 * i] : ((const int*)p)[i];
}

// 8 bf16 (one uint4) FMA into acc[8]; unpack via bit-ops (lo: u<<16, hi: u&0xFFFF0000)
__device__ __forceinline__ void fma8(float* acc, float a, uint4 g) {
    unsigned int u[4] = {g.x, g.y, g.z, g.w};
#pragma unroll
    for (int i = 0; i < 4; i++) {
        union { unsigned int i; float f; } lo, hi;
        lo.i = u[i] << 16;
        hi.i = u[i] & 0xFFFF0000u;
        acc[2 * i]     += a * lo.f;
        acc[2 * i + 1] += a * hi.f;
    }
}
__device__ __forceinline__ void mul8(float* acc, float a, uint4 g) {
    unsigned int u[4] = {g.x, g.y, g.z, g.w};
#pragma unroll
    for (int i = 0; i < 4; i++) {
        union { unsigned int i; float f; } lo, hi;
        lo.i = u[i] << 16;
        hi.i = u[i] & 0xFFFF0000u;
        acc[2 * i]     = a * lo.f;
        acc[2 * i + 1] = a * hi.f;
    }
}

// ---------------- dtype detection (1 block) ----------------
__global__ void detect_kernel(const unsigned short* __restrict__ xr,
                              const unsigned int* __restrict__ eir,
                              int* __restrict__ flags) {
    __shared__ int sF, sI;
    if (threadIdx.x == 0) { sF = 0; sI = 0; }
    __syncthreads();
    int t = threadIdx.x;
    int cf = 0, ci = 0;
#pragma unroll
    for (int i = 0; i < 4; i++) {
        unsigned short u = xr[2 * (t * 4 + i)];
        int e = (u >> 7) & 0xFF;
        if (e >= 100 && e <= 140) cf++;
        unsigned int v = eir[2 * (t * 4 + i) + 1];
        if (v == 0u) ci++;
    }
    atomicAdd(&sF, cf);
    atomicAdd(&sI, ci);
    __syncthreads();
    if (threadIdx.x == 0) {
        flags[0] = (sF >= 614) ? 0 : 1;   // 1 -> float inputs are f32
        flags[1] = (sI >= 512) ? 1 : 0;   // 1 -> edge_index is i64
    }
}

// ---------------- prep: M1 fold + W1/W2 transpose to bf16 ----------------
__global__ void prep_kernel(const void* __restrict__ We1,
                            const void* __restrict__ att_e,
                            const void* __restrict__ W1,
                            const void* __restrict__ W2,
                            const int* __restrict__ flags,
                            float* __restrict__ M1,
                            unsigned short* __restrict__ Wt1,
                            unsigned short* __restrict__ Wt2) {
    int isF32 = flags[0];
    int id = blockIdx.x * 256 + threadIdx.x;
    if (id < 384) {
        int k = id / 12, h = id % 12;
        float s = 0.f;
        for (int c = 0; c < 32; c++)
            s += ldf(We1, (size_t)k * HC + h * 32 + c, isF32) *
                 ldf(att_e, (size_t)h * 32 + c, isF32);
        M1[k * 12 + h] = s;
        return;
    }
    int id1 = id - 384;
    if (id1 < 384 * 256) {
        int n = id1 / 256, k = id1 % 256;
        Wt1[(size_t)n * 256 + k] = f2bf(ldf(W1, (size_t)k * HC + n, isF32));
        return;
    }
    int id2 = id1 - 384 * 256;
    if (id2 < 384 * 384) {
        int n = id2 / 384, k = id2 % 384;
        Wt2[(size_t)n * 384 + k] = f2bf(ldf(W2, (size_t)k * HC + n, isF32));
    }
}

// ---------------- CSR build ----------------
__global__ void hist_kernel(const void* __restrict__ ei, const int* __restrict__ flags,
                            int* __restrict__ cnt) {
    int isI64 = flags[1];
    int e = blockIdx.x * 256 + threadIdx.x;
    if (e < N_EDGES) {
        int d = clampN(ldi(ei, (size_t)N_EDGES + e, isI64));
        atomicAdd(&cnt[d], 1);
    }
}

// 3-phase device-wide scan
__global__ void blockscan_kernel(const int* __restrict__ cnt, int* __restrict__ incl,
                                 int* __restrict__ bsum) {
    __shared__ int buf[256];
    int i = blockIdx.x * 256 + threadIdx.x;
    int v = (i < N_NODES) ? cnt[i] : 0;
    buf[threadIdx.x] = v;
    __syncthreads();
    for (int off = 1; off < 256; off <<= 1) {
        int t = (threadIdx.x >= off) ? buf[threadIdx.x - off] : 0;
        __syncthreads();
        buf[threadIdx.x] += t;
        __syncthreads();
    }
    if (i < N_NODES) incl[i] = buf[threadIdx.x];
    if (threadIdx.x == 255) bsum[blockIdx.x] = buf[255];
}

__global__ void bscan_kernel(const int* __restrict__ bsum, int* __restrict__ boff) {
    __shared__ int buf[128];
    int t = threadIdx.x;
    int v = (t < NBLK) ? bsum[t] : 0;
    buf[t] = v;
    __syncthreads();
    for (int off = 1; off < 128; off <<= 1) {
        int u = (t >= off) ? buf[t - off] : 0;
        __syncthreads();
        buf[t] += u;
        __syncthreads();
    }
    if (t < NBLK) boff[t] = buf[t] - v;
}

__global__ void finalize_kernel(const int* __restrict__ incl, const int* __restrict__ boff,
                                const int* __restrict__ cnt,
                                int* __restrict__ rowptr, int* __restrict__ wofs) {
    int i = blockIdx.x * 256 + threadIdx.x;
    if (i == 0) rowptr[0] = 0;
    if (i < N_NODES) {
        int v = incl[i] + boff[blockIdx.x];
        rowptr[i + 1] = v;
        wofs[i] = v - cnt[i];
    }
}

// minimal scatter: 8 bytes per edge (src, edge_id)
__global__ void scatter_kernel(const void* __restrict__ ei, const int* __restrict__ flags,
                               int* __restrict__ wofs, int2* __restrict__ pairs) {
    int isI64 = flags[1];
    int e = blockIdx.x * 256 + threadIdx.x;
    if (e >= N_EDGES) return;
    int d = clampN(ldi(ei, (size_t)N_EDGES + e, isI64));
    int pos = atomicAdd(&wofs[d], 1);
    if ((unsigned)pos >= (unsigned)N_EDGES) return;
    pairs[pos] = make_int2(clampN(ldi(ei, (size_t)e, isI64)), e);
}

// folded edge attention in coalesced edge order
__global__ void ae_kernel(const void* __restrict__ ea, const int* __restrict__ flags,
                          const float* __restrict__ M1,
                          unsigned short* __restrict__ ae_edge) {
    __shared__ float sM[384];
    for (int i = threadIdx.x; i < 384; i += 256) sM[i] = M1[i];
    __syncthreads();
    int isF32 = flags[0];
    int e = blockIdx.x * 256 + threadIdx.x;
    if (e >= N_EDGES) return;
    float a[32];
    if (isF32) {
        const float4* r4 = (const float4*)((const float*)ea + (size_t)e * 32);
#pragma unroll
        for (int i = 0; i < 8; i++) {
            float4 v = r4[i];
            a[4 * i] = v.x; a[4 * i + 1] = v.y; a[4 * i + 2] = v.z; a[4 * i + 3] = v.w;
        }
    } else {
        const unsigned short* r = (const unsigned short*)ea + (size_t)e * 32;
#pragma unroll
        for (int i = 0; i < 32; i++) a[i] = bf2f(r[i]);
    }
    float ev[12];
#pragma unroll
    for (int h = 0; h < 12; h++) ev[h] = 0.f;
#pragma unroll
    for (int k = 0; k < 32; k++)
#pragma unroll
        for (int h = 0; h < 12; h++) ev[h] += a[k] * sM[k * 12 + h];
    unsigned int w[6];
#pragma unroll
    for (int i = 0; i < 6; i++)
        w[i] = (unsigned int)f2bf(ev[2 * i]) | ((unsigned int)f2bf(ev[2 * i + 1]) << 16);
    uint2* dst = (uint2*)(ae_edge + (size_t)e * 12);
    dst[0] = make_uint2(w[0], w[1]);
    dst[1] = make_uint2(w[2], w[3]);
    dst[2] = make_uint2(w[4], w[5]);
}

// ---------------- full-N MFMA GEMM + fused att logits ----------------
// 512-thread blocks, 8 waves; wave = 16 rows x 192 cols (12 accs).
// Epilogue also computes a_s/a_d per (row, head) from the f32 accumulators:
// wave's half (c0) covers complete heads (0-5 or 6-11); per-lane 24 FMAs
// against LDS att vectors, then 4-stage shfl_xor over the 16 column-lanes.
// Saves the separate att_kernel pass (full 19.2 MB hx re-read) per layer.
__global__ __launch_bounds__(512) void gemm_mfma(const void* __restrict__ A,
                                                 const unsigned short* __restrict__ Bt,
                                                 const int* __restrict__ flags,
                                                 int aFromFlag,
                                                 const void* __restrict__ att_src,
                                                 const void* __restrict__ att_dst,
                                                 unsigned short* __restrict__ C,
                                                 float* __restrict__ a_s,
                                                 float* __restrict__ a_d,
                                                 int M, int K) {
    __shared__ unsigned short sB[384 * BPAD];   // 30720 B
    __shared__ float sS[384];
    __shared__ float sD[384];
    int isF32 = flags[0];
    int aF32 = aFromFlag ? isF32 : 0;
    for (int i = threadIdx.x; i < 384; i += 512) {
        sS[i] = ldf(att_src, (size_t)i, isF32);
        sD[i] = ldf(att_dst, (size_t)i, isF32);
    }
    int lane = threadIdx.x & 63;
    int w = threadIdx.x >> 6;            // 0..7
    int m0 = blockIdx.x * 64 + (w >> 1) * 16;
    int c0 = (w & 1) * 192;
    int r = lane & 15, q = lane >> 4;
    int row = m0 + r;
    if (row >= M) row = M - 1;
    floatx4 acc[12];
#pragma unroll
    for (int j = 0; j < 12; j++) acc[j] = (floatx4){0.f, 0.f, 0.f, 0.f};
    for (int k0 = 0; k0 < K; k0 += 32) {
        for (int i = threadIdx.x; i < 384 * 4; i += 512) {
            int col = i >> 2, seg = i & 3;
            *(uint4*)(sB + (size_t)col * BPAD + seg * 8) =
                *(const uint4*)(Bt + (size_t)col * K + k0 + seg * 8);
        }
        __syncthreads();
        short8 a;
        if (aF32) {
            const float4* ap = (const float4*)((const float*)A + (size_t)row * K + k0 + q * 8);
            float4 u = ap[0], v = ap[1];
            a[0] = (short)f2bf(u.x); a[1] = (short)f2bf(u.y);
            a[2] = (short)f2bf(u.z); a[3] = (short)f2bf(u.w);
            a[4] = (short)f2bf(v.x); a[5] = (short)f2bf(v.y);
            a[6] = (short)f2bf(v.z); a[7] = (short)f2bf(v.w);
        } else {
            a = *(const short8*)((const unsigned short*)A + (size_t)row * K + k0 + q * 8);
        }
#pragma unroll
        for (int j = 0; j < 12; j++) {
            int col = c0 + 16 * j + r;
            short8 b = *(const short8*)(sB + (size_t)col * BPAD + q * 8);
            acc[j] = __builtin_amdgcn_mfma_f32_16x16x32_bf16(a, b, acc[j], 0, 0, 0);
        }
        __syncthreads();
    }
#pragma unroll
    for (int j = 0; j < 12; j++) {
        int col = c0 + 16 * j + r;
#pragma unroll
        for (int t = 0; t < 4; t++) {
            int orow = m0 + q * 4 + t;
            if (orow < M) C[(size_t)orow * HC + col] = f2bf(acc[j][t]);
        }
    }
    // ---- fused att logits from f32 accs ----
    int hb = (w & 1) * 6;   // head base for this wave's half
    float ps[6][4], pd[6][4];
#pragma unroll
    for (int hh = 0; hh < 6; hh++)
#pragma unroll
        for (int t = 0; t < 4; t++) { ps[hh][t] = 0.f; pd[hh][t] = 0.f; }
#pragma unroll
    for (int j = 0; j < 12; j++) {
        int hh = j >> 1;
        int ch = 16 * (j & 1) + r;
        float vs = sS[(hb + hh) * 32 + ch];
        float vd = sD[(hb + hh) * 32 + ch];
#pragma unroll
        for (int t = 0; t < 4; t++) {
            ps[hh][t] += acc[j][t] * vs;
            pd[hh][t] += acc[j][t] * vd;
        }
    }
#pragma unroll
    for (int m = 1; m < 16; m <<= 1) {
#pragma unroll
        for (int hh = 0; hh < 6; hh++)
#pragma unroll
            for (int t = 0; t < 4; t++) {
                ps[hh][t] += __shfl_xor(ps[hh][t], m);
                pd[hh][t] += __shfl_xor(pd[hh][t], m);
            }
    }
    if (r == 0) {
#pragma unroll
        for (int t = 0; t < 4; t++) {
            int orow = m0 + q * 4 + t;
            if (orow < M) {
#pragma unroll
                for (int hh = 0; hh < 6; hh++) {
                    a_s[orow * 12 + hb + hh] = ps[hh][t];
                    a_d[orow * 12 + hb + hh] = pd[hh][t];
                }
            }
        }
    }
}

// ---------------- segment softmax: thread = (node, head) ----------------
__global__ __launch_bounds__(256) void softmax_kernel(const float* __restrict__ a_s,
                                                      const float* __restrict__ a_d,
                                                      const int* __restrict__ rowptr,
                                                      const int2* __restrict__ pairs,
                                                      const unsigned short* __restrict__ ae_edge,
                                                      unsigned short* __restrict__ alpha_e,
                                                      float* __restrict__ exl_out,
                                                      float* __restrict__ rden_out,
                                                      int has_ae) {
    int id = blockIdx.x * 256 + threadIdx.x;
    if (id >= N_NODES * NHEAD) return;
    int node = id / NHEAD;
    int h = id - node * NHEAD;
    int start = rowptr[node], end = rowptr[node + 1];
    if (start < 0) start = 0;
    if (end > N_EDGES) end = N_EDGES;
    int deg = end - start;
    float adn = a_d[id];
    float asn = a_s[id];
    float mx = -1e30f, sae = 0.f;
    // pass 1: segment max + edge-attn sum
    for (int p = start; p < end; p += 2) {
        int2 pe0 = pairs[p];
        bool two = (p + 1 < end);
        int2 pe1 = two ? pairs[p + 1] : pe0;
        int s0 = clampN(pe0.x), s1 = clampN(pe1.x);
        float v0 = a_s[(size_t)s0 * NHEAD + h] + adn;
        float v1 = a_s[(size_t)s1 * NHEAD + h] + adn;
        if (has_ae) {
            int e0 = ((unsigned)pe0.y < (unsigned)N_EDGES) ? pe0.y : 0;
            int e1 = ((unsigned)pe1.y < (unsigned)N_EDGES) ? pe1.y : 0;
            float a0 = bf2f(ae_edge[(size_t)e0 * NHEAD + h]);
            float a1 = bf2f(ae_edge[(size_t)e1 * NHEAD + h]);
            v0 += a0; sae += a0;
            if (two) { v1 += a1; sae += a1; }
        }
        v0 = v0 > 0.f ? v0 : NEG_SLOPE * v0;
        v1 = v1 > 0.f ? v1 : NEG_SLOPE * v1;
        mx = fmaxf(mx, v0);
        if (two) mx = fmaxf(mx, v1);
    }
    float invdeg = 1.f / fmaxf((float)deg, 1.f);
    float el = asn + adn + (has_ae ? sae * invdeg : 0.f);
    el = el > 0.f ? el : NEG_SLOPE * el;
    mx = fmaxf(mx, el);
    // pass 2: recompute v (f32-exact), exp, store unnormalized alpha, denom
    float den = 0.f;
    for (int p = start; p < end; p += 2) {
        int2 pe0 = pairs[p];
        bool two = (p + 1 < end);
        int2 pe1 = two ? pairs[p + 1] : pe0;
        int s0 = clampN(pe0.x), s1 = clampN(pe1.x);
        float v0 = a_s[(size_t)s0 * NHEAD + h] + adn;
        float v1 = a_s[(size_t)s1 * NHEAD + h] + adn;
        if (has_ae) {
            int e0 = ((unsigned)pe0.y < (unsigned)N_EDGES) ? pe0.y : 0;
            int e1 = ((unsigned)pe1.y < (unsigned)N_EDGES) ? pe1.y : 0;
            v0 += bf2f(ae_edge[(size_t)e0 * NHEAD + h]);
            v1 += bf2f(ae_edge[(size_t)e1 * NHEAD + h]);
        }
        v0 = v0 > 0.f ? v0 : NEG_SLOPE * v0;
        v1 = v1 > 0.f ? v1 : NEG_SLOPE * v1;
        float ex0 = expf(v0 - mx);
        float ex1 = expf(v1 - mx);
        alpha_e[(size_t)p * NHEAD + h] = f2bf(ex0);
        den += ex0;
        if (two) {
            alpha_e[(size_t)(p + 1) * NHEAD + h] = f2bf(ex1);
            den += ex1;
        }
    }
    float exl = expf(el - mx);
    exl_out[id] = exl;
    rden_out[id] = 1.f / (den + exl);
}

// ---------------- layer-1 aggregation: lane = 8 contiguous channels ----------------
// Round-4 proven structure: 48 active lanes, 4 nodes/block, pairs software
// pipeline (next batch's pairs loaded before current batch's FMAs).
// Accumulation order = p ascending (bitwise-stable h1).
__global__ __launch_bounds__(256) void agg1_kernel(const unsigned short* __restrict__ hx,
                                                   const unsigned short* __restrict__ alpha_e,
                                                   const float* __restrict__ exl,
                                                   const float* __restrict__ rden,
                                                   const int* __restrict__ rowptr,
                                                   const int2* __restrict__ pairs,
                                                   const void* __restrict__ b1,
                                                   const int* __restrict__ flags,
                                                   unsigned short* __restrict__ h1) {
    int isF32 = flags[0];
    int lane = threadIdx.x & 63;
    int node = blockIdx.x * 4 + (threadIdx.x >> 6);
    if (node >= N_NODES || lane >= 48) return;
    int h = lane >> 2;        // head 0..11
    int off = lane * 8;       // channel base
    int start = rowptr[node], end = rowptr[node + 1];
    if (start < 0) start = 0;
    if (end > N_EDGES) end = N_EDGES;
    float acc[8];
    {
        uint4 g = *(const uint4*)(hx + (size_t)node * HC + off);
        mul8(acc, exl[node * 12 + h], g);
    }
    int p = start;
    int2 pe0, pe1, pe2, pe3;
    bool have = (p + 4 <= end);
    if (have) {
        pe0 = pairs[p]; pe1 = pairs[p + 1]; pe2 = pairs[p + 2]; pe3 = pairs[p + 3];
    }
    while (have) {
        int2 c0 = pe0, c1 = pe1, c2 = pe2, c3 = pe3;
        bool nxt = (p + 8 <= end);
        if (nxt) {
            pe0 = pairs[p + 4]; pe1 = pairs[p + 5]; pe2 = pairs[p + 6]; pe3 = pairs[p + 7];
        }
        uint4 g0 = *(const uint4*)(hx + (size_t)clampN(c0.x) * HC + off);
        uint4 g1 = *(const uint4*)(hx + (size_t)clampN(c1.x) * HC + off);
        uint4 g2 = *(const uint4*)(hx + (size_t)clampN(c2.x) * HC + off);
        uint4 g3 = *(const uint4*)(hx + (size_t)clampN(c3.x) * HC + off);
        float a0 = bf2f(alpha_e[(size_t)p * 12 + h]);
        float a1 = bf2f(alpha_e[(size_t)(p + 1) * 12 + h]);
        float a2 = bf2f(alpha_e[(size_t)(p + 2) * 12 + h]);
        float a3 = bf2f(alpha_e[(size_t)(p + 3) * 12 + h]);
        fma8(acc, a0, g0);
        fma8(acc, a1, g1);
        fma8(acc, a2, g2);
        fma8(acc, a3, g3);
        p += 4;
        have = nxt;
    }
    for (; p < end; p++) {
        int2 pe = pairs[p];
        uint4 g = *(const uint4*)(hx + (size_t)clampN(pe.x) * HC + off);
        float a = bf2f(alpha_e[(size_t)p * 12 + h]);
        fma8(acc, a, g);
    }
    float rd = rden[node * 12 + h];
    unsigned int w[4];
#pragma unroll
    for (int i = 0; i < 4; i++) {
        float v0 = acc[2 * i] * rd + ldf(b1, (size_t)(off + 2 * i), isF32);
        float v1 = acc[2 * i + 1] * rd + ldf(b1, (size_t)(off + 2 * i + 1), isF32);
        v0 = v0 > 0.f ? v0 : expm1f(v0);
        v1 = v1 > 0.f ? v1 : expm1f(v1);
        w[i] = (unsigned int)f2bf(v0) | ((unsigned int)f2bf(v1) << 16);
    }
    *(uint4*)(h1 + (size_t)node * HC + off) = make_uint4(w[0], w[1], w[2], w[3]);
}

// ---------------- layer-2 aggregation + head-mean + bias + log_softmax ----------------
// Round-4 proven structure (48-lane node-wave + pairs software pipeline).
__global__ __launch_bounds__(256) void agg2_kernel(const unsigned short* __restrict__ hx,
                                                   const unsigned short* __restrict__ alpha_e,
                                                   const float* __restrict__ exl,
                                                   const float* __restrict__ rden,
                                                   const int* __restrict__ rowptr,
                                                   const int2* __restrict__ pairs,
                                                   const void* __restrict__ b2,
                                                   const int* __restrict__ flags,
                                                   float* __restrict__ out) {
    int isF32 = flags[0];
    int lane = threadIdx.x & 63;
    int node = blockIdx.x * 4 + (threadIdx.x >> 6);
    if (node >= N_NODES) return;
    bool act = lane < 48;
    int h = act ? (lane >> 2) : 0;
    int off = act ? lane * 8 : 0;
    float acc[8];
#pragma unroll
    for (int k = 0; k < 8; k++) acc[k] = 0.f;
    if (act) {
        int start = rowptr[node], end = rowptr[node + 1];
        if (start < 0) start = 0;
        if (end > N_EDGES) end = N_EDGES;
        {
            uint4 g = *(const uint4*)(hx + (size_t)node * HC + off);
            mul8(acc, exl[node * 12 + h], g);
        }
        int p = start;
        int2 pe0, pe1, pe2, pe3;
        bool have = (p + 4 <= end);
        if (have) {
            pe0 = pairs[p]; pe1 = pairs[p + 1]; pe2 = pairs[p + 2]; pe3 = pairs[p + 3];
        }
        while (have) {
            int2 c0 = pe0, c1 = pe1, c2 = pe2, c3 = pe3;
            bool nxt = (p + 8 <= end);
            if (nxt) {
                pe0 = pairs[p + 4]; pe1 = pairs[p + 5]; pe2 = pairs[p + 6]; pe3 = pairs[p + 7];
            }
            uint4 g0 = *(const uint4*)(hx + (size_t)clampN(c0.x) * HC + off);
            uint4 g1 = *(const uint4*)(hx + (size_t)clampN(c1.x) * HC + off);
            uint4 g2 = *(const uint4*)(hx + (size_t)clampN(c2.x) * HC + off);
            uint4 g3 = *(const uint4*)(hx + (size_t)clampN(c3.x) * HC + off);
            float a0 = bf2f(alpha_e[(size_t)p * 12 + h]);
            float a1 = bf2f(alpha_e[(size_t)(p + 1) * 12 + h]);
            float a2 = bf2f(alpha_e[(size_t)(p + 2) * 12 + h]);
            float a3 = bf2f(alpha_e[(size_t)(p + 3) * 12 + h]);
            fma8(acc, a0, g0);
            fma8(acc, a1, g1);
            fma8(acc, a2, g2);
            fma8(acc, a3, g3);
            p += 4;
            have = nxt;
        }
        for (; p < end; p++) {
            int2 pe = pairs[p];
            uint4 g = *(const uint4*)(hx + (size_t)clampN(pe.x) * HC + off);
            float a = bf2f(alpha_e[(size_t)p * 12 + h]);
            fma8(acc, a, g);
        }
        float rd = rden[node * 12 + h];
#pragma unroll
        for (int k = 0; k < 8; k++) acc[k] *= rd;
    }
    // reduce over 12 heads: lanes {L, L+16, L+32} then butterfly over h bits
#pragma unroll
    for (int k = 0; k < 8; k++) {
        float t1 = __shfl(acc[k], lane + 16);
        float t2 = __shfl(acc[k], lane + 32);
        acc[k] += t1 + t2;
        acc[k] += __shfl_xor(acc[k], 4);
        acc[k] += __shfl_xor(acc[k], 8);
    }
    if (lane < 4) {
        int q = lane;
        float hv[8];
        float m = -1e30f;
#pragma unroll
        for (int t = 0; t < 8; t++) {
            hv[t] = acc[t] * (1.f / 12.f) + ldf(b2, (size_t)(8 * q + t), isF32);
            m = fmaxf(m, hv[t]);
        }
        m = fmaxf(m, __shfl_xor(m, 1));
        m = fmaxf(m, __shfl_xor(m, 2));
        float s = 0.f;
#pragma unroll
        for (int t = 0; t < 8; t++) s += expf(hv[t] - m);
        s += __shfl_xor(s, 1);
        s += __shfl_xor(s, 2);
        float ls = m + logf(s);
        float4* o0 = (float4*)(out + (size_t)node * 32 + 8 * q);
        float4* l0 = (float4*)(out + (size_t)N_NODES * 32 + (size_t)node * 32 + 8 * q);
        o0[0] = make_float4(hv[0], hv[1], hv[2], hv[3]);
        o0[1] = make_float4(hv[4], hv[5], hv[6], hv[7]);
        l0[0] = make_float4(hv[0] - ls, hv[1] - ls, hv[2] - ls, hv[3] - ls);
        l0[1] = make_float4(hv[4] - ls, hv[5] - ls, hv[6] - ls, hv[7] - ls);
    }
}

extern "C" void kernel_launch(void* const* d_in, const int* in_sizes, int n_in,
                              void* d_out, int out_size, void* d_ws, size_t ws_size,
                              hipStream_t stream) {
    const void* x        = d_in[0];
    const void* ei       = d_in[1];
    const void* ea       = d_in[2];
    const void* W1       = d_in[3];
    const void* att_src1 = d_in[4];
    const void* att_dst1 = d_in[5];
    const void* We1      = d_in[6];
    const void* att_e1   = d_in[7];
    const void* b1       = d_in[8];
    const void* W2       = d_in[9];
    const void* att_src2 = d_in[10];
    const void* att_dst2 = d_in[11];
    const void* b2       = d_in[12];
    float* out = (float*)d_out;

    char* ws = (char*)d_ws;
    size_t off = 0;
    auto alloc = [&](size_t bytes) -> void* {
        void* p = ws + off;
        off = (off + bytes + 255) & ~(size_t)255;
        return p;
    };
    int*            flags   = (int*)alloc(16);
    float*          M1      = (float*)alloc((size_t)384 * 4);
    int*            rowptr  = (int*)alloc((size_t)(N_NODES + 1) * 4);
    int*            cnt     = (int*)alloc((size_t)N_NODES * 4);
    int*            wofs    = (int*)alloc((size_t)N_NODES * 4);
    int*            incl    = (int*)alloc((size_t)N_NODES * 4);
    int*            bsum    = (int*)alloc((size_t)NBLK * 4);
    int*            boff    = (int*)alloc((size_t)NBLK * 4);
    float*          a_s     = (float*)alloc((size_t)N_NODES * 12 * 4);
    float*          a_d     = (float*)alloc((size_t)N_NODES * 12 * 4);
    float*          exl     = (float*)alloc((size_t)N_NODES * 12 * 4);
    float*          rden    = (float*)alloc((size_t)N_NODES * 12 * 4);
    int2*           pairs   = (int2*)alloc((size_t)N_EDGES * 8);
    unsigned short* alpha_e = (unsigned short*)alloc((size_t)N_EDGES * 12 * 2);
    unsigned short* hx      = (unsigned short*)alloc((size_t)N_NODES * HC * 2);
    // h1 aliases ae_edge: ae_edge dead after softmax1, h1 born in agg1 (after).
    unsigned short* h1      = (unsigned short*)alloc((size_t)N_NODES * HC * 2);
    unsigned short* ae_edge = h1;
    unsigned short* Wt1     = (unsigned short*)alloc((size_t)384 * 256 * 2);
    unsigned short* Wt2     = (unsigned short*)alloc((size_t)384 * 384 * 2);

    hipMemsetAsync(cnt, 0, (size_t)N_NODES * 4, stream);
    detect_kernel<<<1, 256, 0, stream>>>((const unsigned short*)x, (const unsigned int*)ei, flags);
    prep_kernel<<<(384 + 384 * 256 + 384 * 384 + 255) / 256, 256, 0, stream>>>(
        We1, att_e1, W1, W2, flags, M1, Wt1, Wt2);
    hist_kernel<<<(N_EDGES + 255) / 256, 256, 0, stream>>>(ei, flags, cnt);
    blockscan_kernel<<<NBLK, 256, 0, stream>>>(cnt, incl, bsum);
    bscan_kernel<<<1, 128, 0, stream>>>(bsum, boff);
    finalize_kernel<<<NBLK, 256, 0, stream>>>(incl, boff, cnt, rowptr, wofs);
    scatter_kernel<<<(N_EDGES + 255) / 256, 256, 0, stream>>>(ei, flags, wofs, pairs);
    ae_kernel<<<(N_EDGES + 255) / 256, 256, 0, stream>>>(ea, flags, M1, ae_edge);
    // layer 1 (att fused into GEMM epilogue)
    gemm_mfma<<<(N_NODES + 63) / 64, 512, 0, stream>>>(x, Wt1, flags, 1, att_src1, att_dst1,
                                                       hx, a_s, a_d, N_NODES, NFEAT);
    softmax_kernel<<<(N_NODES * 12 + 255) / 256, 256, 0, stream>>>(a_s, a_d, rowptr, pairs,
                                                                   ae_edge, alpha_e, exl, rden, 1);
    agg1_kernel<<<(N_NODES + 3) / 4, 256, 0, stream>>>(hx, alpha_e, exl, rden, rowptr, pairs,
                                                       b1, flags, h1);
    // layer 2 (att fused into GEMM epilogue)
    gemm_mfma<<<(N_NODES + 63) / 64, 512, 0, stream>>>(h1, Wt2, flags, 0, att_src2, att_dst2,
                                                       hx, a_s, a_d, N_NODES, HC);
    softmax_kernel<<<(N_NODES * 12 + 255) / 256, 256, 0, stream>>>(a_s, a_d, rowptr, pairs,
                                                                   ae_edge, alpha_e, exl, rden, 0);
    agg2_kernel<<<(N_NODES + 3) / 4, 256, 0, stream>>>(hx, alpha_e, exl, rden, rowptr, pairs,
                                                       b2, flags, out);
}

// Round 7
// 417.170 us; speedup vs baseline: 1.1302x; 1.0248x over previous
//
#include <hip/hip_runtime.h>
#include <hip/hip_bf16.h>
#include <math.h>

#define N_NODES 25000
#define N_EDGES 400000
#define NFEAT   256
#define NHID    32
#define NHEAD   12
#define HC      384
#define HCX     416   // HC + 32 folded att columns (12 a_s, 4 pad, 12 a_d, 4 pad)
#define NEG_SLOPE 0.2f
#define NBLK    ((N_NODES + 255) / 256)
#define BPAD    40   // LDS row pitch for B-tile (2-way bank aliasing only)

typedef __attribute__((ext_vector_type(8))) short short8;
typedef __attribute__((ext_vector_type(4))) float floatx4;

__device__ __forceinline__ float bf2f(unsigned short u) {
    union { unsigned int i; float f; } v; v.i = ((unsigned int)u) << 16; return v.f;
}
__device__ __forceinline__ unsigned short f2bf(float f) {
    union { float f; unsigned int i; } v; v.f = f;
    unsigned int x = v.i;
    unsigned int r = (x + 0x7FFFu + ((x >> 16) & 1u)) >> 16;
    return (unsigned short)r;
}
__device__ __forceinline__ int clampN(int s) {
    return ((unsigned)s < (unsigned)N_NODES) ? s : 0;
}
__device__ __forceinline__ float ldf(const void* p, size_t i, int isF32) {
    return isF32 ? ((const float*)p)[i] : bf2f(((const unsigned short*)p)[i]);
}
__device__ __forceinline__ int ldi(const void* p, size_t i, int isI64) {
    return isI64 ? (int)((const unsigned int*)p)[2 * i] : ((const int*)p)[i];
}

// 8 bf16 (one uint4) FMA into acc[8]; unpack via bit-ops (lo: u<<16, hi: u&0xFFFF0000)
__device__ __forceinline__ void fma8(float* acc, float a, uint4 g) {
    unsigned int u[4] = {g.x, g.y, g.z, g.w};
#pragma unroll
    for (int i = 0; i < 4; i++) {
        union { unsigned int i; float f; } lo, hi;
        lo.i = u[i] << 16;
        hi.i = u[i] & 0xFFFF0000u;
        acc[2 * i]     += a * lo.f;
        acc[2 * i + 1] += a * hi.f;
    }
}
__device__ __forceinline__ void mul8(float* acc, float a, uint4 g) {
    unsigned int u[4] = {g.x, g.y, g.z, g.w};
#pragma unroll
    for (int i = 0; i < 4; i++) {
        union { unsigned int i; float f; } lo, hi;
        lo.i = u[i] << 16;
        hi.i = u[i] & 0xFFFF0000u;
        acc[2 * i]     = a * lo.f;
        acc[2 * i + 1] = a * hi.f;
    }
}

// ---------------- dtype detection (1 block) ----------------
__global__ void detect_kernel(const unsigned short* __restrict__ xr,
                              const unsigned int* __restrict__ eir,
                              int* __restrict__ flags) {
    __shared__ int sF, sI;
    if (threadIdx.x == 0) { sF = 0; sI = 0; }
    __syncthreads();
    int t = threadIdx.x;
    int cf = 0, ci = 0;
#pragma unroll
    for (int i = 0; i < 4; i++) {
        unsigned short u = xr[2 * (t * 4 + i)];
        int e = (u >> 7) & 0xFF;
        if (e >= 100 && e <= 140) cf++;
        unsigned int v = eir[2 * (t * 4 + i) + 1];
        if (v == 0u) ci++;
    }
    atomicAdd(&sF, cf);
    atomicAdd(&sI, ci);
    __syncthreads();
    if (threadIdx.x == 0) {
        flags[0] = (sF >= 614) ? 0 : 1;   // 1 -> float inputs are f32
        flags[1] = (sI >= 512) ? 1 : 0;   // 1 -> edge_index is i64
    }
}

// ---------------- prep: M1 fold + W transposes + folded att columns ----------------
// Wt1/Wt2 are HCX columns wide: cols 0..383 = W^T; 384..395 = M_s[k,h] =
// sum_c W[k,h*32+c]*att_src[h,c]; 400..411 = M_d; 396-399/412-415 = 0.
// With these columns, the GEMM's extra tile computes a_s/a_d directly.
__global__ void prep_kernel(const void* __restrict__ We1,
                            const void* __restrict__ att_e,
                            const void* __restrict__ W1,
                            const void* __restrict__ W2,
                            const void* __restrict__ as1,
                            const void* __restrict__ ad1,
                            const void* __restrict__ as2,
                            const void* __restrict__ ad2,
                            const int* __restrict__ flags,
                            float* __restrict__ M1,
                            unsigned short* __restrict__ Wt1,
                            unsigned short* __restrict__ Wt2) {
    int isF32 = flags[0];
    int id = blockIdx.x * 256 + threadIdx.x;
    if (id < 384) {
        int k = id / 12, h = id % 12;
        float s = 0.f;
        for (int c = 0; c < 32; c++)
            s += ldf(We1, (size_t)k * HC + h * 32 + c, isF32) *
                 ldf(att_e, (size_t)h * 32 + c, isF32);
        M1[k * 12 + h] = s;
        return;
    }
    int id1 = id - 384;
    if (id1 < HCX * 256) {
        int n = id1 / 256, k = id1 % 256;
        unsigned short v = 0;
        if (n < 384) {
            v = f2bf(ldf(W1, (size_t)k * HC + n, isF32));
        } else if (n < 400) {
            int h = n - 384;
            if (h < 12) {
                float s = 0.f;
                for (int c = 0; c < 32; c++)
                    s += ldf(W1, (size_t)k * HC + h * 32 + c, isF32) *
                         ldf(as1, (size_t)h * 32 + c, isF32);
                v = f2bf(s);
            }
        } else {
            int h = n - 400;
            if (h < 12) {
                float s = 0.f;
                for (int c = 0; c < 32; c++)
                    s += ldf(W1, (size_t)k * HC + h * 32 + c, isF32) *
                         ldf(ad1, (size_t)h * 32 + c, isF32);
                v = f2bf(s);
            }
        }
        Wt1[(size_t)n * 256 + k] = v;
        return;
    }
    int id2 = id1 - HCX * 256;
    if (id2 < HCX * 384) {
        int n = id2 / 384, k = id2 % 384;
        unsigned short v = 0;
        if (n < 384) {
            v = f2bf(ldf(W2, (size_t)k * HC + n, isF32));
        } else if (n < 400) {
            int h = n - 384;
            if (h < 12) {
                float s = 0.f;
                for (int c = 0; c < 32; c++)
                    s += ldf(W2, (size_t)k * HC + h * 32 + c, isF32) *
                         ldf(as2, (size_t)h * 32 + c, isF32);
                v = f2bf(s);
            }
        } else {
            int h = n - 400;
            if (h < 12) {
                float s = 0.f;
                for (int c = 0; c < 32; c++)
                    s += ldf(W2, (size_t)k * HC + h * 32 + c, isF32) *
                         ldf(ad2, (size_t)h * 32 + c, isF32);
                v = f2bf(s);
            }
        }
        Wt2[(size_t)n * 384 + k] = v;
    }
}

// ---------------- CSR build ----------------
__global__ void hist_kernel(const void* __restrict__ ei, const int* __restrict__ flags,
                            int* __restrict__ cnt) {
    int isI64 = flags[1];
    int e = blockIdx.x * 256 + threadIdx.x;
    if (e < N_EDGES) {
        int d = clampN(ldi(ei, (size_t)N_EDGES + e, isI64));
        atomicAdd(&cnt[d], 1);
    }
}

// 3-phase device-wide scan
__global__ void blockscan_kernel(const int* __restrict__ cnt, int* __restrict__ incl,
                                 int* __restrict__ bsum) {
    __shared__ int buf[256];
    int i = blockIdx.x * 256 + threadIdx.x;
    int v = (i < N_NODES) ? cnt[i] : 0;
    buf[threadIdx.x] = v;
    __syncthreads();
    for (int off = 1; off < 256; off <<= 1) {
        int t = (threadIdx.x >= off) ? buf[threadIdx.x - off] : 0;
        __syncthreads();
        buf[threadIdx.x] += t;
        __syncthreads();
    }
    if (i < N_NODES) incl[i] = buf[threadIdx.x];
    if (threadIdx.x == 255) bsum[blockIdx.x] = buf[255];
}

__global__ void bscan_kernel(const int* __restrict__ bsum, int* __restrict__ boff) {
    __shared__ int buf[128];
    int t = threadIdx.x;
    int v = (t < NBLK) ? bsum[t] : 0;
    buf[t] = v;
    __syncthreads();
    for (int off = 1; off < 128; off <<= 1) {
        int u = (t >= off) ? buf[t - off] : 0;
        __syncthreads();
        buf[t] += u;
        __syncthreads();
    }
    if (t < NBLK) boff[t] = buf[t] - v;
}

__global__ void finalize_kernel(const int* __restrict__ incl, const int* __restrict__ boff,
                                const int* __restrict__ cnt,
                                int* __restrict__ rowptr, int* __restrict__ wofs) {
    int i = blockIdx.x * 256 + threadIdx.x;
    if (i == 0) rowptr[0] = 0;
    if (i < N_NODES) {
        int v = incl[i] + boff[blockIdx.x];
        rowptr[i + 1] = v;
        wofs[i] = v - cnt[i];
    }
}

// minimal scatter: 8 bytes per edge (src, edge_id)
__global__ void scatter_kernel(const void* __restrict__ ei, const int* __restrict__ flags,
                               int* __restrict__ wofs, int2* __restrict__ pairs) {
    int isI64 = flags[1];
    int e = blockIdx.x * 256 + threadIdx.x;
    if (e >= N_EDGES) return;
    int d = clampN(ldi(ei, (size_t)N_EDGES + e, isI64));
    int pos = atomicAdd(&wofs[d], 1);
    if ((unsigned)pos >= (unsigned)N_EDGES) return;
    pairs[pos] = make_int2(clampN(ldi(ei, (size_t)e, isI64)), e);
}

// folded edge attention in coalesced edge order
__global__ void ae_kernel(const void* __restrict__ ea, const int* __restrict__ flags,
                          const float* __restrict__ M1,
                          unsigned short* __restrict__ ae_edge) {
    __shared__ float sM[384];
    for (int i = threadIdx.x; i < 384; i += 256) sM[i] = M1[i];
    __syncthreads();
    int isF32 = flags[0];
    int e = blockIdx.x * 256 + threadIdx.x;
    if (e >= N_EDGES) return;
    float a[32];
    if (isF32) {
        const float4* r4 = (const float4*)((const float*)ea + (size_t)e * 32);
#pragma unroll
        for (int i = 0; i < 8; i++) {
            float4 v = r4[i];
            a[4 * i] = v.x; a[4 * i + 1] = v.y; a[4 * i + 2] = v.z; a[4 * i + 3] = v.w;
        }
    } else {
        const unsigned short* r = (const unsigned short*)ea + (size_t)e * 32;
#pragma unroll
        for (int i = 0; i < 32; i++) a[i] = bf2f(r[i]);
    }
    float ev[12];
#pragma unroll
    for (int h = 0; h < 12; h++) ev[h] = 0.f;
#pragma unroll
    for (int k = 0; k < 32; k++)
#pragma unroll
        for (int h = 0; h < 12; h++) ev[h] += a[k] * sM[k * 12 + h];
    unsigned int w[6];
#pragma unroll
    for (int i = 0; i < 6; i++)
        w[i] = (unsigned int)f2bf(ev[2 * i]) | ((unsigned int)f2bf(ev[2 * i + 1]) << 16);
    uint2* dst = (uint2*)(ae_edge + (size_t)e * 12);
    dst[0] = make_uint2(w[0], w[1]);
    dst[1] = make_uint2(w[2], w[3]);
    dst[2] = make_uint2(w[4], w[5]);
}

// ---------------- full-N MFMA GEMM with folded att columns ----------------
// 512-thread blocks, 8 waves; wave = 16 rows x 192 cols (12 tiles) + 1 extra
// tile of folded att columns: even waves -> a_s (cols 384-399), odd waves ->
// a_d (cols 400-415). Epilogue for att = 4 scalar stores from acc[12], no shfl.
__global__ __launch_bounds__(512) void gemm_mfma(const void* __restrict__ A,
                                                 const unsigned short* __restrict__ Bt,
                                                 const int* __restrict__ flags,
                                                 int aFromFlag,
                                                 unsigned short* __restrict__ C,
                                                 float* __restrict__ a_s,
                                                 float* __restrict__ a_d,
                                                 int M, int K) {
    __shared__ unsigned short sB[HCX * BPAD];   // 33280 B
    int aF32 = aFromFlag ? flags[0] : 0;
    int lane = threadIdx.x & 63;
    int w = threadIdx.x >> 6;            // 0..7
    int m0 = blockIdx.x * 64 + (w >> 1) * 16;
    int c0 = (w & 1) * 192;
    int ecol = 384 + (w & 1) * 16;       // extra-tile column base
    int r = lane & 15, q = lane >> 4;
    int row = m0 + r;
    if (row >= M) row = M - 1;
    floatx4 acc[13];
#pragma unroll
    for (int j = 0; j < 13; j++) acc[j] = (floatx4){0.f, 0.f, 0.f, 0.f};
    for (int k0 = 0; k0 < K; k0 += 32) {
        // stage B-ext tile: 416 cols x 32 k = 1664 16B-chunks / 512 threads
        for (int i = threadIdx.x; i < HCX * 4; i += 512) {
            int col = i >> 2, seg = i & 3;
            *(uint4*)(sB + (size_t)col * BPAD + seg * 8) =
                *(const uint4*)(Bt + (size_t)col * K + k0 + seg * 8);
        }
        __syncthreads();
        short8 a;
        if (aF32) {
            const float4* ap = (const float4*)((const float*)A + (size_t)row * K + k0 + q * 8);
            float4 u = ap[0], v = ap[1];
            a[0] = (short)f2bf(u.x); a[1] = (short)f2bf(u.y);
            a[2] = (short)f2bf(u.z); a[3] = (short)f2bf(u.w);
            a[4] = (short)f2bf(v.x); a[5] = (short)f2bf(v.y);
            a[6] = (short)f2bf(v.z); a[7] = (short)f2bf(v.w);
        } else {
            a = *(const short8*)((const unsigned short*)A + (size_t)row * K + k0 + q * 8);
        }
#pragma unroll
        for (int j = 0; j < 12; j++) {
            int col = c0 + 16 * j + r;
            short8 b = *(const short8*)(sB + (size_t)col * BPAD + q * 8);
            acc[j] = __builtin_amdgcn_mfma_f32_16x16x32_bf16(a, b, acc[j], 0, 0, 0);
        }
        {
            short8 b = *(const short8*)(sB + (size_t)(ecol + r) * BPAD + q * 8);
            acc[12] = __builtin_amdgcn_mfma_f32_16x16x32_bf16(a, b, acc[12], 0, 0, 0);
        }
        __syncthreads();
    }
#pragma unroll
    for (int j = 0; j < 12; j++) {
        int col = c0 + 16 * j + r;
#pragma unroll
        for (int t = 0; t < 4; t++) {
            int orow = m0 + q * 4 + t;
            if (orow < M) C[(size_t)orow * HC + col] = f2bf(acc[j][t]);
        }
    }
    if (r < 12) {
        float* dst = (w & 1) ? a_d : a_s;
#pragma unroll
        for (int t = 0; t < 4; t++) {
            int orow = m0 + q * 4 + t;
            if (orow < M) dst[orow * 12 + r] = acc[12][t];
        }
    }
}

// ---------------- segment softmax: thread = (node, head) ----------------
__global__ __launch_bounds__(256) void softmax_kernel(const float* __restrict__ a_s,
                                                      const float* __restrict__ a_d,
                                                      const int* __restrict__ rowptr,
                                                      const int2* __restrict__ pairs,
                                                      const unsigned short* __restrict__ ae_edge,
                                                      unsigned short* __restrict__ alpha_e,
                                                      float* __restrict__ exl_out,
                                                      float* __restrict__ rden_out,
                                                      int has_ae) {
    int id = blockIdx.x * 256 + threadIdx.x;
    if (id >= N_NODES * NHEAD) return;
    int node = id / NHEAD;
    int h = id - node * NHEAD;
    int start = rowptr[node], end = rowptr[node + 1];
    if (start < 0) start = 0;
    if (end > N_EDGES) end = N_EDGES;
    int deg = end - start;
    float adn = a_d[id];
    float asn = a_s[id];
    float mx = -1e30f, sae = 0.f;
    // pass 1: segment max + edge-attn sum
    for (int p = start; p < end; p += 2) {
        int2 pe0 = pairs[p];
        bool two = (p + 1 < end);
        int2 pe1 = two ? pairs[p + 1] : pe0;
        int s0 = clampN(pe0.x), s1 = clampN(pe1.x);
        float v0 = a_s[(size_t)s0 * NHEAD + h] + adn;
        float v1 = a_s[(size_t)s1 * NHEAD + h] + adn;
        if (has_ae) {
            int e0 = ((unsigned)pe0.y < (unsigned)N_EDGES) ? pe0.y : 0;
            int e1 = ((unsigned)pe1.y < (unsigned)N_EDGES) ? pe1.y : 0;
            float a0 = bf2f(ae_edge[(size_t)e0 * NHEAD + h]);
            float a1 = bf2f(ae_edge[(size_t)e1 * NHEAD + h]);
            v0 += a0; sae += a0;
            if (two) { v1 += a1; sae += a1; }
        }
        v0 = v0 > 0.f ? v0 : NEG_SLOPE * v0;
        v1 = v1 > 0.f ? v1 : NEG_SLOPE * v1;
        mx = fmaxf(mx, v0);
        if (two) mx = fmaxf(mx, v1);
    }
    float invdeg = 1.f / fmaxf((float)deg, 1.f);
    float el = asn + adn + (has_ae ? sae * invdeg : 0.f);
    el = el > 0.f ? el : NEG_SLOPE * el;
    mx = fmaxf(mx, el);
    // pass 2: recompute v (f32-exact), exp, store unnormalized alpha, denom
    float den = 0.f;
    for (int p = start; p < end; p += 2) {
        int2 pe0 = pairs[p];
        bool two = (p + 1 < end);
        int2 pe1 = two ? pairs[p + 1] : pe0;
        int s0 = clampN(pe0.x), s1 = clampN(pe1.x);
        float v0 = a_s[(size_t)s0 * NHEAD + h] + adn;
        float v1 = a_s[(size_t)s1 * NHEAD + h] + adn;
        if (has_ae) {
            int e0 = ((unsigned)pe0.y < (unsigned)N_EDGES) ? pe0.y : 0;
            int e1 = ((unsigned)pe1.y < (unsigned)N_EDGES) ? pe1.y : 0;
            v0 += bf2f(ae_edge[(size_t)e0 * NHEAD + h]);
            v1 += bf2f(ae_edge[(size_t)e1 * NHEAD + h]);
        }
        v0 = v0 > 0.f ? v0 : NEG_SLOPE * v0;
        v1 = v1 > 0.f ? v1 : NEG_SLOPE * v1;
        float ex0 = expf(v0 - mx);
        float ex1 = expf(v1 - mx);
        alpha_e[(size_t)p * NHEAD + h] = f2bf(ex0);
        den += ex0;
        if (two) {
            alpha_e[(size_t)(p + 1) * NHEAD + h] = f2bf(ex1);
            den += ex1;
        }
    }
    float exl = expf(el - mx);
    exl_out[id] = exl;
    rden_out[id] = 1.f / (den + exl);
}

// ---------------- layer-1 aggregation: lane = 8 contiguous channels ----------------
// Round-4 proven structure: 48 active lanes, 4 nodes/block, pairs software
// pipeline (next batch's pairs loaded before current batch's FMAs).
// Accumulation order = p ascending (bitwise-stable h1).
__global__ __launch_bounds__(256) void agg1_kernel(const unsigned short* __restrict__ hx,
                                                   const unsigned short* __restrict__ alpha_e,
                                                   const float* __restrict__ exl,
                                                   const float* __restrict__ rden,
                                                   const int* __restrict__ rowptr,
                                                   const int2* __restrict__ pairs,
                                                   const void* __restrict__ b1,
                                                   const int* __restrict__ flags,
                                                   unsigned short* __restrict__ h1) {
    int isF32 = flags[0];
    int lane = threadIdx.x & 63;
    int node = blockIdx.x * 4 + (threadIdx.x >> 6);
    if (node >= N_NODES || lane >= 48) return;
    int h = lane >> 2;        // head 0..11
    int off = lane * 8;       // channel base
    int start = rowptr[node], end = rowptr[node + 1];
    if (start < 0) start = 0;
    if (end > N_EDGES) end = N_EDGES;
    float acc[8];
    {
        uint4 g = *(const uint4*)(hx + (size_t)node * HC + off);
        mul8(acc, exl[node * 12 + h], g);
    }
    int p = start;
    int2 pe0, pe1, pe2, pe3;
    bool have = (p + 4 <= end);
    if (have) {
        pe0 = pairs[p]; pe1 = pairs[p + 1]; pe2 = pairs[p + 2]; pe3 = pairs[p + 3];
    }
    while (have) {
        int2 c0 = pe0, c1 = pe1, c2 = pe2, c3 = pe3;
        bool nxt = (p + 8 <= end);
        if (nxt) {
            pe0 = pairs[p + 4]; pe1 = pairs[p + 5]; pe2 = pairs[p + 6]; pe3 = pairs[p + 7];
        }
        uint4 g0 = *(const uint4*)(hx + (size_t)clampN(c0.x) * HC + off);
        uint4 g1 = *(const uint4*)(hx + (size_t)clampN(c1.x) * HC + off);
        uint4 g2 = *(const uint4*)(hx + (size_t)clampN(c2.x) * HC + off);
        uint4 g3 = *(const uint4*)(hx + (size_t)clampN(c3.x) * HC + off);
        float a0 = bf2f(alpha_e[(size_t)p * 12 + h]);
        float a1 = bf2f(alpha_e[(size_t)(p + 1) * 12 + h]);
        float a2 = bf2f(alpha_e[(size_t)(p + 2) * 12 + h]);
        float a3 = bf2f(alpha_e[(size_t)(p + 3) * 12 + h]);
        fma8(acc, a0, g0);
        fma8(acc, a1, g1);
        fma8(acc, a2, g2);
        fma8(acc, a3, g3);
        p += 4;
        have = nxt;
    }
    for (; p < end; p++) {
        int2 pe = pairs[p];
        uint4 g = *(const uint4*)(hx + (size_t)clampN(pe.x) * HC + off);
        float a = bf2f(alpha_e[(size_t)p * 12 + h]);
        fma8(acc, a, g);
    }
    float rd = rden[node * 12 + h];
    unsigned int w[4];
#pragma unroll
    for (int i = 0; i < 4; i++) {
        float v0 = acc[2 * i] * rd + ldf(b1, (size_t)(off + 2 * i), isF32);
        float v1 = acc[2 * i + 1] * rd + ldf(b1, (size_t)(off + 2 * i + 1), isF32);
        v0 = v0 > 0.f ? v0 : expm1f(v0);
        v1 = v1 > 0.f ? v1 : expm1f(v1);
        w[i] = (unsigned int)f2bf(v0) | ((unsigned int)f2bf(v1) << 16);
    }
    *(uint4*)(h1 + (size_t)node * HC + off) = make_uint4(w[0], w[1], w[2], w[3]);
}

// ---------------- layer-2 aggregation + head-mean + bias + log_softmax ----------------
// Round-4 proven structure (48-lane node-wave + pairs software pipeline).
__global__ __launch_bounds__(256) void agg2_kernel(const unsigned short* __restrict__ hx,
                                                   const unsigned short* __restrict__ alpha_e,
                                                   const float* __restrict__ exl,
                                                   const float* __restrict__ rden,
                                                   const int* __restrict__ rowptr,
                                                   const int2* __restrict__ pairs,
                                                   const void* __restrict__ b2,
                                                   const int* __restrict__ flags,
                                                   float* __restrict__ out) {
    int isF32 = flags[0];
    int lane = threadIdx.x & 63;
    int node = blockIdx.x * 4 + (threadIdx.x >> 6);
    if (node >= N_NODES) return;
    bool act = lane < 48;
    int h = act ? (lane >> 2) : 0;
    int off = act ? lane * 8 : 0;
    float acc[8];
#pragma unroll
    for (int k = 0; k < 8; k++) acc[k] = 0.f;
    if (act) {
        int start = rowptr[node], end = rowptr[node + 1];
        if (start < 0) start = 0;
        if (end > N_EDGES) end = N_EDGES;
        {
            uint4 g = *(const uint4*)(hx + (size_t)node * HC + off);
            mul8(acc, exl[node * 12 + h], g);
        }
        int p = start;
        int2 pe0, pe1, pe2, pe3;
        bool have = (p + 4 <= end);
        if (have) {
            pe0 = pairs[p]; pe1 = pairs[p + 1]; pe2 = pairs[p + 2]; pe3 = pairs[p + 3];
        }
        while (have) {
            int2 c0 = pe0, c1 = pe1, c2 = pe2, c3 = pe3;
            bool nxt = (p + 8 <= end);
            if (nxt) {
                pe0 = pairs[p + 4]; pe1 = pairs[p + 5]; pe2 = pairs[p + 6]; pe3 = pairs[p + 7];
            }
            uint4 g0 = *(const uint4*)(hx + (size_t)clampN(c0.x) * HC + off);
            uint4 g1 = *(const uint4*)(hx + (size_t)clampN(c1.x) * HC + off);
            uint4 g2 = *(const uint4*)(hx + (size_t)clampN(c2.x) * HC + off);
            uint4 g3 = *(const uint4*)(hx + (size_t)clampN(c3.x) * HC + off);
            float a0 = bf2f(alpha_e[(size_t)p * 12 + h]);
            float a1 = bf2f(alpha_e[(size_t)(p + 1) * 12 + h]);
            float a2 = bf2f(alpha_e[(size_t)(p + 2) * 12 + h]);
            float a3 = bf2f(alpha_e[(size_t)(p + 3) * 12 + h]);
            fma8(acc, a0, g0);
            fma8(acc, a1, g1);
            fma8(acc, a2, g2);
            fma8(acc, a3, g3);
            p += 4;
            have = nxt;
        }
        for (; p < end; p++) {
            int2 pe = pairs[p];
            uint4 g = *(const uint4*)(hx + (size_t)clampN(pe.x) * HC + off);
            float a = bf2f(alpha_e[(size_t)p * 12 + h]);
            fma8(acc, a, g);
        }
        float rd = rden[node * 12 + h];
#pragma unroll
        for (int k = 0; k < 8; k++) acc[k] *= rd;
    }
    // reduce over 12 heads: lanes {L, L+16, L+32} then butterfly over h bits
#pragma unroll
    for (int k = 0; k < 8; k++) {
        float t1 = __shfl(acc[k], lane + 16);
        float t2 = __shfl(acc[k], lane + 32);
        acc[k] += t1 + t2;
        acc[k] += __shfl_xor(acc[k], 4);
        acc[k] += __shfl_xor(acc[k], 8);
    }
    if (lane < 4) {
        int q = lane;
        float hv[8];
        float m = -1e30f;
#pragma unroll
        for (int t = 0; t < 8; t++) {
            hv[t] = acc[t] * (1.f / 12.f) + ldf(b2, (size_t)(8 * q + t), isF32);
            m = fmaxf(m, hv[t]);
        }
        m = fmaxf(m, __shfl_xor(m, 1));
        m = fmaxf(m, __shfl_xor(m, 2));
        float s = 0.f;
#pragma unroll
        for (int t = 0; t < 8; t++) s += expf(hv[t] - m);
        s += __shfl_xor(s, 1);
        s += __shfl_xor(s, 2);
        float ls = m + logf(s);
        float4* o0 = (float4*)(out + (size_t)node * 32 + 8 * q);
        float4* l0 = (float4*)(out + (size_t)N_NODES * 32 + (size_t)node * 32 + 8 * q);
        o0[0] = make_float4(hv[0], hv[1], hv[2], hv[3]);
        o0[1] = make_float4(hv[4], hv[5], hv[6], hv[7]);
        l0[0] = make_float4(hv[0] - ls, hv[1] - ls, hv[2] - ls, hv[3] - ls);
        l0[1] = make_float4(hv[4] - ls, hv[5] - ls, hv[6] - ls, hv[7] - ls);
    }
}

extern "C" void kernel_launch(void* const* d_in, const int* in_sizes, int n_in,
                              void* d_out, int out_size, void* d_ws, size_t ws_size,
                              hipStream_t stream) {
    const void* x        = d_in[0];
    const void* ei       = d_in[1];
    const void* ea       = d_in[2];
    const void* W1       = d_in[3];
    const void* att_src1 = d_in[4];
    const void* att_dst1 = d_in[5];
    const void* We1      = d_in[6];
    const void* att_e1   = d_in[7];
    const void* b1       = d_in[8];
    const void* W2       = d_in[9];
    const void* att_src2 = d_in[10];
    const void* att_dst2 = d_in[11];
    const void* b2       = d_in[12];
    float* out = (float*)d_out;

    char* ws = (char*)d_ws;
    size_t off = 0;
    auto alloc = [&](size_t bytes) -> void* {
        void* p = ws + off;
        off = (off + bytes + 255) & ~(size_t)255;
        return p;
    };
    int*            flags   = (int*)alloc(16);
    float*          M1      = (float*)alloc((size_t)384 * 4);
    int*            rowptr  = (int*)alloc((size_t)(N_NODES + 1) * 4);
    int*            cnt     = (int*)alloc((size_t)N_NODES * 4);
    int*            wofs    = (int*)alloc((size_t)N_NODES * 4);
    int*            incl    = (int*)alloc((size_t)N_NODES * 4);
    int*            bsum    = (int*)alloc((size_t)NBLK * 4);
    int*            boff    = (int*)alloc((size_t)NBLK * 4);
    float*          a_s     = (float*)alloc((size_t)N_NODES * 12 * 4);
    float*          a_d     = (float*)alloc((size_t)N_NODES * 12 * 4);
    float*          exl     = (float*)alloc((size_t)N_NODES * 12 * 4);
    float*          rden    = (float*)alloc((size_t)N_NODES * 12 * 4);
    int2*           pairs   = (int2*)alloc((size_t)N_EDGES * 8);
    unsigned short* alpha_e = (unsigned short*)alloc((size_t)N_EDGES * 12 * 2);
    unsigned short* hx      = (unsigned short*)alloc((size_t)N_NODES * HC * 2);
    // h1 aliases ae_edge: ae_edge dead after softmax1, h1 born in agg1 (after).
    unsigned short* h1      = (unsigned short*)alloc((size_t)N_NODES * HC * 2);
    unsigned short* ae_edge = h1;
    unsigned short* Wt1     = (unsigned short*)alloc((size_t)HCX * 256 * 2);
    unsigned short* Wt2     = (unsigned short*)alloc((size_t)HCX * 384 * 2);

    hipMemsetAsync(cnt, 0, (size_t)N_NODES * 4, stream);
    detect_kernel<<<1, 256, 0, stream>>>((const unsigned short*)x, (const unsigned int*)ei, flags);
    prep_kernel<<<(384 + HCX * 256 + HCX * 384 + 255) / 256, 256, 0, stream>>>(
        We1, att_e1, W1, W2, att_src1, att_dst1, att_src2, att_dst2, flags, M1, Wt1, Wt2);
    hist_kernel<<<(N_EDGES + 255) / 256, 256, 0, stream>>>(ei, flags, cnt);
    blockscan_kernel<<<NBLK, 256, 0, stream>>>(cnt, incl, bsum);
    bscan_kernel<<<1, 128, 0, stream>>>(bsum, boff);
    finalize_kernel<<<NBLK, 256, 0, stream>>>(incl, boff, cnt, rowptr, wofs);
    scatter_kernel<<<(N_EDGES + 255) / 256, 256, 0, stream>>>(ei, flags, wofs, pairs);
    ae_kernel<<<(N_EDGES + 255) / 256, 256, 0, stream>>>(ea, flags, M1, ae_edge);
    // layer 1 (att logits via folded B columns)
    gemm_mfma<<<(N_NODES + 63) / 64, 512, 0, stream>>>(x, Wt1, flags, 1, hx, a_s, a_d,
                                                       N_NODES, NFEAT);
    softmax_kernel<<<(N_NODES * 12 + 255) / 256, 256, 0, stream>>>(a_s, a_d, rowptr, pairs,
                                                                   ae_edge, alpha_e, exl, rden, 1);
    agg1_kernel<<<(N_NODES + 3) / 4, 256, 0, stream>>>(hx, alpha_e, exl, rden, rowptr, pairs,
                                                       b1, flags, h1);
    // layer 2 (att logits via folded B columns)
    gemm_mfma<<<(N_NODES + 63) / 64, 512, 0, stream>>>(h1, Wt2, flags, 0, hx, a_s, a_d,
                                                       N_NODES, HC);
    softmax_kernel<<<(N_NODES * 12 + 255) / 256, 256, 0, stream>>>(a_s, a_d, rowptr, pairs,
                                                                   ae_edge, alpha_e, exl, rden, 0);
    agg2_kernel<<<(N_NODES + 3) / 4, 256, 0, stream>>>(hx, alpha_e, exl, rden, rowptr, pairs,
                                                       b2, flags, out);
}

// Round 8
// 407.774 us; speedup vs baseline: 1.1562x; 1.0230x over previous
//
#include <hip/hip_runtime.h>
#include <hip/hip_bf16.h>
#include <math.h>

#define N_NODES 25000
#define N_EDGES 400000
#define NFEAT   256
#define NHID    32
#define NHEAD   12
#define HC      384
#define HCX     416   // HC + 32 folded att columns (12 a_s, 4 pad, 12 a_d, 4 pad)
#define NEG_SLOPE 0.2f
#define NBLK    ((N_NODES + 255) / 256)
#define BPAD    40   // LDS row pitch for B-tile (2-way bank aliasing only)

typedef __attribute__((ext_vector_type(8))) short short8;
typedef __attribute__((ext_vector_type(4))) float floatx4;

__device__ __forceinline__ float bf2f(unsigned short u) {
    union { unsigned int i; float f; } v; v.i = ((unsigned int)u) << 16; return v.f;
}
__device__ __forceinline__ unsigned short f2bf(float f) {
    union { float f; unsigned int i; } v; v.f = f;
    unsigned int x = v.i;
    unsigned int r = (x + 0x7FFFu + ((x >> 16) & 1u)) >> 16;
    return (unsigned short)r;
}
__device__ __forceinline__ int clampN(int s) {
    return ((unsigned)s < (unsigned)N_NODES) ? s : 0;
}
__device__ __forceinline__ float ldf(const void* p, size_t i, int isF32) {
    return isF32 ? ((const float*)p)[i] : bf2f(((const unsigned short*)p)[i]);
}
__device__ __forceinline__ int ldi(const void* p, size_t i, int isI64) {
    return isI64 ? (int)((const unsigned int*)p)[2 * i] : ((const int*)p)[i];
}

// 8 bf16 (one uint4) FMA into acc[8]; unpack via bit-ops (lo: u<<16, hi: u&0xFFFF0000)
__device__ __forceinline__ void fma8(float* acc, float a, uint4 g) {
    unsigned int u[4] = {g.x, g.y, g.z, g.w};
#pragma unroll
    for (int i = 0; i < 4; i++) {
        union { unsigned int i; float f; } lo, hi;
        lo.i = u[i] << 16;
        hi.i = u[i] & 0xFFFF0000u;
        acc[2 * i]     += a * lo.f;
        acc[2 * i + 1] += a * hi.f;
    }
}
__device__ __forceinline__ void mul8(float* acc, float a, uint4 g) {
    unsigned int u[4] = {g.x, g.y, g.z, g.w};
#pragma unroll
    for (int i = 0; i < 4; i++) {
        union { unsigned int i; float f; } lo, hi;
        lo.i = u[i] << 16;
        hi.i = u[i] & 0xFFFF0000u;
        acc[2 * i]     = a * lo.f;
        acc[2 * i + 1] = a * hi.f;
    }
}

// ---------------- dtype detection (1 block) ----------------
__global__ void detect_kernel(const unsigned short* __restrict__ xr,
                              const unsigned int* __restrict__ eir,
                              int* __restrict__ flags) {
    __shared__ int sF, sI;
    if (threadIdx.x == 0) { sF = 0; sI = 0; }
    __syncthreads();
    int t = threadIdx.x;
    int cf = 0, ci = 0;
#pragma unroll
    for (int i = 0; i < 4; i++) {
        unsigned short u = xr[2 * (t * 4 + i)];
        int e = (u >> 7) & 0xFF;
        if (e >= 100 && e <= 140) cf++;
        unsigned int v = eir[2 * (t * 4 + i) + 1];
        if (v == 0u) ci++;
    }
    atomicAdd(&sF, cf);
    atomicAdd(&sI, ci);
    __syncthreads();
    if (threadIdx.x == 0) {
        flags[0] = (sF >= 614) ? 0 : 1;   // 1 -> float inputs are f32
        flags[1] = (sI >= 512) ? 1 : 0;   // 1 -> edge_index is i64
    }
}

// ---------------- prep: M1 fold + W transposes + folded att columns ----------------
// Wt1/Wt2 are HCX columns wide: cols 0..383 = W^T; 384..395 = M_s[k,h] =
// sum_c W[k,h*32+c]*att_src[h,c]; 400..411 = M_d; 396-399/412-415 = 0.
// With these columns, the GEMM's extra tile computes a_s/a_d directly.
__global__ void prep_kernel(const void* __restrict__ We1,
                            const void* __restrict__ att_e,
                            const void* __restrict__ W1,
                            const void* __restrict__ W2,
                            const void* __restrict__ as1,
                            const void* __restrict__ ad1,
                            const void* __restrict__ as2,
                            const void* __restrict__ ad2,
                            const int* __restrict__ flags,
                            float* __restrict__ M1,
                            unsigned short* __restrict__ Wt1,
                            unsigned short* __restrict__ Wt2) {
    int isF32 = flags[0];
    int id = blockIdx.x * 256 + threadIdx.x;
    if (id < 384) {
        int k = id / 12, h = id % 12;
        float s = 0.f;
        for (int c = 0; c < 32; c++)
            s += ldf(We1, (size_t)k * HC + h * 32 + c, isF32) *
                 ldf(att_e, (size_t)h * 32 + c, isF32);
        M1[k * 12 + h] = s;
        return;
    }
    int id1 = id - 384;
    if (id1 < HCX * 256) {
        int n = id1 / 256, k = id1 % 256;
        unsigned short v = 0;
        if (n < 384) {
            v = f2bf(ldf(W1, (size_t)k * HC + n, isF32));
        } else if (n < 400) {
            int h = n - 384;
            if (h < 12) {
                float s = 0.f;
                for (int c = 0; c < 32; c++)
                    s += ldf(W1, (size_t)k * HC + h * 32 + c, isF32) *
                         ldf(as1, (size_t)h * 32 + c, isF32);
                v = f2bf(s);
            }
        } else {
            int h = n - 400;
            if (h < 12) {
                float s = 0.f;
                for (int c = 0; c < 32; c++)
                    s += ldf(W1, (size_t)k * HC + h * 32 + c, isF32) *
                         ldf(ad1, (size_t)h * 32 + c, isF32);
                v = f2bf(s);
            }
        }
        Wt1[(size_t)n * 256 + k] = v;
        return;
    }
    int id2 = id1 - HCX * 256;
    if (id2 < HCX * 384) {
        int n = id2 / 384, k = id2 % 384;
        unsigned short v = 0;
        if (n < 384) {
            v = f2bf(ldf(W2, (size_t)k * HC + n, isF32));
        } else if (n < 400) {
            int h = n - 384;
            if (h < 12) {
                float s = 0.f;
                for (int c = 0; c < 32; c++)
                    s += ldf(W2, (size_t)k * HC + h * 32 + c, isF32) *
                         ldf(as2, (size_t)h * 32 + c, isF32);
                v = f2bf(s);
            }
        } else {
            int h = n - 400;
            if (h < 12) {
                float s = 0.f;
                for (int c = 0; c < 32; c++)
                    s += ldf(W2, (size_t)k * HC + h * 32 + c, isF32) *
                         ldf(ad2, (size_t)h * 32 + c, isF32);
                v = f2bf(s);
            }
        }
        Wt2[(size_t)n * 384 + k] = v;
    }
}

// ---------------- CSR build ----------------
__global__ void hist_kernel(const void* __restrict__ ei, const int* __restrict__ flags,
                            int* __restrict__ cnt) {
    int isI64 = flags[1];
    int e = blockIdx.x * 256 + threadIdx.x;
    if (e < N_EDGES) {
        int d = clampN(ldi(ei, (size_t)N_EDGES + e, isI64));
        atomicAdd(&cnt[d], 1);
    }
}

// 3-phase device-wide scan
__global__ void blockscan_kernel(const int* __restrict__ cnt, int* __restrict__ incl,
                                 int* __restrict__ bsum) {
    __shared__ int buf[256];
    int i = blockIdx.x * 256 + threadIdx.x;
    int v = (i < N_NODES) ? cnt[i] : 0;
    buf[threadIdx.x] = v;
    __syncthreads();
    for (int off = 1; off < 256; off <<= 1) {
        int t = (threadIdx.x >= off) ? buf[threadIdx.x - off] : 0;
        __syncthreads();
        buf[threadIdx.x] += t;
        __syncthreads();
    }
    if (i < N_NODES) incl[i] = buf[threadIdx.x];
    if (threadIdx.x == 255) bsum[blockIdx.x] = buf[255];
}

__global__ void bscan_kernel(const int* __restrict__ bsum, int* __restrict__ boff) {
    __shared__ int buf[128];
    int t = threadIdx.x;
    int v = (t < NBLK) ? bsum[t] : 0;
    buf[t] = v;
    __syncthreads();
    for (int off = 1; off < 128; off <<= 1) {
        int u = (t >= off) ? buf[t - off] : 0;
        __syncthreads();
        buf[t] += u;
        __syncthreads();
    }
    if (t < NBLK) boff[t] = buf[t] - v;
}

__global__ void finalize_kernel(const int* __restrict__ incl, const int* __restrict__ boff,
                                const int* __restrict__ cnt,
                                int* __restrict__ rowptr, int* __restrict__ wofs) {
    int i = blockIdx.x * 256 + threadIdx.x;
    if (i == 0) rowptr[0] = 0;
    if (i < N_NODES) {
        int v = incl[i] + boff[blockIdx.x];
        rowptr[i + 1] = v;
        wofs[i] = v - cnt[i];
    }
}

// minimal scatter: 8 bytes per edge (src, edge_id)
__global__ void scatter_kernel(const void* __restrict__ ei, const int* __restrict__ flags,
                               int* __restrict__ wofs, int2* __restrict__ pairs) {
    int isI64 = flags[1];
    int e = blockIdx.x * 256 + threadIdx.x;
    if (e >= N_EDGES) return;
    int d = clampN(ldi(ei, (size_t)N_EDGES + e, isI64));
    int pos = atomicAdd(&wofs[d], 1);
    if ((unsigned)pos >= (unsigned)N_EDGES) return;
    pairs[pos] = make_int2(clampN(ldi(ei, (size_t)e, isI64)), e);
}

// folded edge attention, written in CSR ORDER: thread p gathers its edge's
// attr row (random 128 B read, latency hidden by 400K independent threads)
// and writes ae[p*12+h] sequentially. Softmax then reads ae STREAMING
// instead of the old random 9.6 MB x 2-pass gather (L2-miss per record).
// Identical values, different storage order -> bitwise-identical outputs.
__global__ void ae_kernel(const void* __restrict__ ea, const int* __restrict__ flags,
                          const float* __restrict__ M1,
                          const int2* __restrict__ pairs,
                          unsigned short* __restrict__ ae_edge) {
    __shared__ float sM[384];
    for (int i = threadIdx.x; i < 384; i += 256) sM[i] = M1[i];
    __syncthreads();
    int isF32 = flags[0];
    int p = blockIdx.x * 256 + threadIdx.x;
    if (p >= N_EDGES) return;
    int eid = pairs[p].y;
    if ((unsigned)eid >= (unsigned)N_EDGES) eid = 0;
    float a[32];
    if (isF32) {
        const float4* r4 = (const float4*)((const float*)ea + (size_t)eid * 32);
#pragma unroll
        for (int i = 0; i < 8; i++) {
            float4 v = r4[i];
            a[4 * i] = v.x; a[4 * i + 1] = v.y; a[4 * i + 2] = v.z; a[4 * i + 3] = v.w;
        }
    } else {
        const unsigned short* r = (const unsigned short*)ea + (size_t)eid * 32;
#pragma unroll
        for (int i = 0; i < 32; i++) a[i] = bf2f(r[i]);
    }
    float ev[12];
#pragma unroll
    for (int h = 0; h < 12; h++) ev[h] = 0.f;
#pragma unroll
    for (int k = 0; k < 32; k++)
#pragma unroll
        for (int h = 0; h < 12; h++) ev[h] += a[k] * sM[k * 12 + h];
    unsigned int w[6];
#pragma unroll
    for (int i = 0; i < 6; i++)
        w[i] = (unsigned int)f2bf(ev[2 * i]) | ((unsigned int)f2bf(ev[2 * i + 1]) << 16);
    uint2* dst = (uint2*)(ae_edge + (size_t)p * 12);
    dst[0] = make_uint2(w[0], w[1]);
    dst[1] = make_uint2(w[2], w[3]);
    dst[2] = make_uint2(w[4], w[5]);
}

// ---------------- full-N MFMA GEMM with folded att columns ----------------
// 512-thread blocks, 8 waves; wave = 16 rows x 192 cols (12 tiles) + 1 extra
// tile of folded att columns: even waves -> a_s (cols 384-399), odd waves ->
// a_d (cols 400-415). Epilogue for att = 4 scalar stores from acc[12], no shfl.
__global__ __launch_bounds__(512) void gemm_mfma(const void* __restrict__ A,
                                                 const unsigned short* __restrict__ Bt,
                                                 const int* __restrict__ flags,
                                                 int aFromFlag,
                                                 unsigned short* __restrict__ C,
                                                 float* __restrict__ a_s,
                                                 float* __restrict__ a_d,
                                                 int M, int K) {
    __shared__ unsigned short sB[HCX * BPAD];   // 33280 B
    int aF32 = aFromFlag ? flags[0] : 0;
    int lane = threadIdx.x & 63;
    int w = threadIdx.x >> 6;            // 0..7
    int m0 = blockIdx.x * 64 + (w >> 1) * 16;
    int c0 = (w & 1) * 192;
    int ecol = 384 + (w & 1) * 16;       // extra-tile column base
    int r = lane & 15, q = lane >> 4;
    int row = m0 + r;
    if (row >= M) row = M - 1;
    floatx4 acc[13];
#pragma unroll
    for (int j = 0; j < 13; j++) acc[j] = (floatx4){0.f, 0.f, 0.f, 0.f};
    for (int k0 = 0; k0 < K; k0 += 32) {
        // stage B-ext tile: 416 cols x 32 k = 1664 16B-chunks / 512 threads
        for (int i = threadIdx.x; i < HCX * 4; i += 512) {
            int col = i >> 2, seg = i & 3;
            *(uint4*)(sB + (size_t)col * BPAD + seg * 8) =
                *(const uint4*)(Bt + (size_t)col * K + k0 + seg * 8);
        }
        __syncthreads();
        short8 a;
        if (aF32) {
            const float4* ap = (const float4*)((const float*)A + (size_t)row * K + k0 + q * 8);
            float4 u = ap[0], v = ap[1];
            a[0] = (short)f2bf(u.x); a[1] = (short)f2bf(u.y);
            a[2] = (short)f2bf(u.z); a[3] = (short)f2bf(u.w);
            a[4] = (short)f2bf(v.x); a[5] = (short)f2bf(v.y);
            a[6] = (short)f2bf(v.z); a[7] = (short)f2bf(v.w);
        } else {
            a = *(const short8*)((const unsigned short*)A + (size_t)row * K + k0 + q * 8);
        }
#pragma unroll
        for (int j = 0; j < 12; j++) {
            int col = c0 + 16 * j + r;
            short8 b = *(const short8*)(sB + (size_t)col * BPAD + q * 8);
            acc[j] = __builtin_amdgcn_mfma_f32_16x16x32_bf16(a, b, acc[j], 0, 0, 0);
        }
        {
            short8 b = *(const short8*)(sB + (size_t)(ecol + r) * BPAD + q * 8);
            acc[12] = __builtin_amdgcn_mfma_f32_16x16x32_bf16(a, b, acc[12], 0, 0, 0);
        }
        __syncthreads();
    }
#pragma unroll
    for (int j = 0; j < 12; j++) {
        int col = c0 + 16 * j + r;
#pragma unroll
        for (int t = 0; t < 4; t++) {
            int orow = m0 + q * 4 + t;
            if (orow < M) C[(size_t)orow * HC + col] = f2bf(acc[j][t]);
        }
    }
    if (r < 12) {
        float* dst = (w & 1) ? a_d : a_s;
#pragma unroll
        for (int t = 0; t < 4; t++) {
            int orow = m0 + q * 4 + t;
            if (orow < M) dst[orow * 12 + r] = acc[12][t];
        }
    }
}

// ---------------- segment softmax: thread = (node, head) ----------------
// ae_edge is now CSR-ordered: read streaming at p*12+h (no random gather).
__global__ __launch_bounds__(256) void softmax_kernel(const float* __restrict__ a_s,
                                                      const float* __restrict__ a_d,
                                                      const int* __restrict__ rowptr,
                                                      const int2* __restrict__ pairs,
                                                      const unsigned short* __restrict__ ae_edge,
                                                      unsigned short* __restrict__ alpha_e,
                                                      float* __restrict__ exl_out,
                                                      float* __restrict__ rden_out,
                                                      int has_ae) {
    int id = blockIdx.x * 256 + threadIdx.x;
    if (id >= N_NODES * NHEAD) return;
    int node = id / NHEAD;
    int h = id - node * NHEAD;
    int start = rowptr[node], end = rowptr[node + 1];
    if (start < 0) start = 0;
    if (end > N_EDGES) end = N_EDGES;
    int deg = end - start;
    float adn = a_d[id];
    float asn = a_s[id];
    float mx = -1e30f, sae = 0.f;
    // pass 1: segment max + edge-attn sum
    for (int p = start; p < end; p += 2) {
        int2 pe0 = pairs[p];
        bool two = (p + 1 < end);
        int2 pe1 = two ? pairs[p + 1] : pe0;
        int s0 = clampN(pe0.x), s1 = clampN(pe1.x);
        float v0 = a_s[(size_t)s0 * NHEAD + h] + adn;
        float v1 = a_s[(size_t)s1 * NHEAD + h] + adn;
        if (has_ae) {
            float a0 = bf2f(ae_edge[(size_t)p * NHEAD + h]);
            float a1 = two ? bf2f(ae_edge[(size_t)(p + 1) * NHEAD + h]) : 0.f;
            v0 += a0; sae += a0;
            if (two) { v1 += a1; sae += a1; }
        }
        v0 = v0 > 0.f ? v0 : NEG_SLOPE * v0;
        v1 = v1 > 0.f ? v1 : NEG_SLOPE * v1;
        mx = fmaxf(mx, v0);
        if (two) mx = fmaxf(mx, v1);
    }
    float invdeg = 1.f / fmaxf((float)deg, 1.f);
    float el = asn + adn + (has_ae ? sae * invdeg : 0.f);
    el = el > 0.f ? el : NEG_SLOPE * el;
    mx = fmaxf(mx, el);
    // pass 2: recompute v (f32-exact), exp, store unnormalized alpha, denom
    float den = 0.f;
    for (int p = start; p < end; p += 2) {
        int2 pe0 = pairs[p];
        bool two = (p + 1 < end);
        int2 pe1 = two ? pairs[p + 1] : pe0;
        int s0 = clampN(pe0.x), s1 = clampN(pe1.x);
        float v0 = a_s[(size_t)s0 * NHEAD + h] + adn;
        float v1 = a_s[(size_t)s1 * NHEAD + h] + adn;
        if (has_ae) {
            v0 += bf2f(ae_edge[(size_t)p * NHEAD + h]);
            if (two) v1 += bf2f(ae_edge[(size_t)(p + 1) * NHEAD + h]);
        }
        v0 = v0 > 0.f ? v0 : NEG_SLOPE * v0;
        v1 = v1 > 0.f ? v1 : NEG_SLOPE * v1;
        float ex0 = expf(v0 - mx);
        float ex1 = expf(v1 - mx);
        alpha_e[(size_t)p * NHEAD + h] = f2bf(ex0);
        den += ex0;
        if (two) {
            alpha_e[(size_t)(p + 1) * NHEAD + h] = f2bf(ex1);
            den += ex1;
        }
    }
    float exl = expf(el - mx);
    exl_out[id] = exl;
    rden_out[id] = 1.f / (den + exl);
}

// ---------------- layer-1 aggregation: lane = 8 contiguous channels ----------------
// Round-4 proven structure: 48 active lanes, 4 nodes/block, pairs software
// pipeline (next batch's pairs loaded before current batch's FMAs).
// Accumulation order = p ascending (bitwise-stable h1).
__global__ __launch_bounds__(256) void agg1_kernel(const unsigned short* __restrict__ hx,
                                                   const unsigned short* __restrict__ alpha_e,
                                                   const float* __restrict__ exl,
                                                   const float* __restrict__ rden,
                                                   const int* __restrict__ rowptr,
                                                   const int2* __restrict__ pairs,
                                                   const void* __restrict__ b1,
                                                   const int* __restrict__ flags,
                                                   unsigned short* __restrict__ h1) {
    int isF32 = flags[0];
    int lane = threadIdx.x & 63;
    int node = blockIdx.x * 4 + (threadIdx.x >> 6);
    if (node >= N_NODES || lane >= 48) return;
    int h = lane >> 2;        // head 0..11
    int off = lane * 8;       // channel base
    int start = rowptr[node], end = rowptr[node + 1];
    if (start < 0) start = 0;
    if (end > N_EDGES) end = N_EDGES;
    float acc[8];
    {
        uint4 g = *(const uint4*)(hx + (size_t)node * HC + off);
        mul8(acc, exl[node * 12 + h], g);
    }
    int p = start;
    int2 pe0, pe1, pe2, pe3;
    bool have = (p + 4 <= end);
    if (have) {
        pe0 = pairs[p]; pe1 = pairs[p + 1]; pe2 = pairs[p + 2]; pe3 = pairs[p + 3];
    }
    while (have) {
        int2 c0 = pe0, c1 = pe1, c2 = pe2, c3 = pe3;
        bool nxt = (p + 8 <= end);
        if (nxt) {
            pe0 = pairs[p + 4]; pe1 = pairs[p + 5]; pe2 = pairs[p + 6]; pe3 = pairs[p + 7];
        }
        uint4 g0 = *(const uint4*)(hx + (size_t)clampN(c0.x) * HC + off);
        uint4 g1 = *(const uint4*)(hx + (size_t)clampN(c1.x) * HC + off);
        uint4 g2 = *(const uint4*)(hx + (size_t)clampN(c2.x) * HC + off);
        uint4 g3 = *(const uint4*)(hx + (size_t)clampN(c3.x) * HC + off);
        float a0 = bf2f(alpha_e[(size_t)p * 12 + h]);
        float a1 = bf2f(alpha_e[(size_t)(p + 1) * 12 + h]);
        float a2 = bf2f(alpha_e[(size_t)(p + 2) * 12 + h]);
        float a3 = bf2f(alpha_e[(size_t)(p + 3) * 12 + h]);
        fma8(acc, a0, g0);
        fma8(acc, a1, g1);
        fma8(acc, a2, g2);
        fma8(acc, a3, g3);
        p += 4;
        have = nxt;
    }
    for (; p < end; p++) {
        int2 pe = pairs[p];
        uint4 g = *(const uint4*)(hx + (size_t)clampN(pe.x) * HC + off);
        float a = bf2f(alpha_e[(size_t)p * 12 + h]);
        fma8(acc, a, g);
    }
    float rd = rden[node * 12 + h];
    unsigned int w[4];
#pragma unroll
    for (int i = 0; i < 4; i++) {
        float v0 = acc[2 * i] * rd + ldf(b1, (size_t)(off + 2 * i), isF32);
        float v1 = acc[2 * i + 1] * rd + ldf(b1, (size_t)(off + 2 * i + 1), isF32);
        v0 = v0 > 0.f ? v0 : expm1f(v0);
        v1 = v1 > 0.f ? v1 : expm1f(v1);
        w[i] = (unsigned int)f2bf(v0) | ((unsigned int)f2bf(v1) << 16);
    }
    *(uint4*)(h1 + (size_t)node * HC + off) = make_uint4(w[0], w[1], w[2], w[3]);
}

// ---------------- layer-2 aggregation + head-mean + bias + log_softmax ----------------
// Round-4 proven structure (48-lane node-wave + pairs software pipeline).
__global__ __launch_bounds__(256) void agg2_kernel(const unsigned short* __restrict__ hx,
                                                   const unsigned short* __restrict__ alpha_e,
                                                   const float* __restrict__ exl,
                                                   const float* __restrict__ rden,
                                                   const int* __restrict__ rowptr,
                                                   const int2* __restrict__ pairs,
                                                   const void* __restrict__ b2,
                                                   const int* __restrict__ flags,
                                                   float* __restrict__ out) {
    int isF32 = flags[0];
    int lane = threadIdx.x & 63;
    int node = blockIdx.x * 4 + (threadIdx.x >> 6);
    if (node >= N_NODES) return;
    bool act = lane < 48;
    int h = act ? (lane >> 2) : 0;
    int off = act ? lane * 8 : 0;
    float acc[8];
#pragma unroll
    for (int k = 0; k < 8; k++) acc[k] = 0.f;
    if (act) {
        int start = rowptr[node], end = rowptr[node + 1];
        if (start < 0) start = 0;
        if (end > N_EDGES) end = N_EDGES;
        {
            uint4 g = *(const uint4*)(hx + (size_t)node * HC + off);
            mul8(acc, exl[node * 12 + h], g);
        }
        int p = start;
        int2 pe0, pe1, pe2, pe3;
        bool have = (p + 4 <= end);
        if (have) {
            pe0 = pairs[p]; pe1 = pairs[p + 1]; pe2 = pairs[p + 2]; pe3 = pairs[p + 3];
        }
        while (have) {
            int2 c0 = pe0, c1 = pe1, c2 = pe2, c3 = pe3;
            bool nxt = (p + 8 <= end);
            if (nxt) {
                pe0 = pairs[p + 4]; pe1 = pairs[p + 5]; pe2 = pairs[p + 6]; pe3 = pairs[p + 7];
            }
            uint4 g0 = *(const uint4*)(hx + (size_t)clampN(c0.x) * HC + off);
            uint4 g1 = *(const uint4*)(hx + (size_t)clampN(c1.x) * HC + off);
            uint4 g2 = *(const uint4*)(hx + (size_t)clampN(c2.x) * HC + off);
            uint4 g3 = *(const uint4*)(hx + (size_t)clampN(c3.x) * HC + off);
            float a0 = bf2f(alpha_e[(size_t)p * 12 + h]);
            float a1 = bf2f(alpha_e[(size_t)(p + 1) * 12 + h]);
            float a2 = bf2f(alpha_e[(size_t)(p + 2) * 12 + h]);
            float a3 = bf2f(alpha_e[(size_t)(p + 3) * 12 + h]);
            fma8(acc, a0, g0);
            fma8(acc, a1, g1);
            fma8(acc, a2, g2);
            fma8(acc, a3, g3);
            p += 4;
            have = nxt;
        }
        for (; p < end; p++) {
            int2 pe = pairs[p];
            uint4 g = *(const uint4*)(hx + (size_t)clampN(pe.x) * HC + off);
            float a = bf2f(alpha_e[(size_t)p * 12 + h]);
            fma8(acc, a, g);
        }
        float rd = rden[node * 12 + h];
#pragma unroll
        for (int k = 0; k < 8; k++) acc[k] *= rd;
    }
    // reduce over 12 heads: lanes {L, L+16, L+32} then butterfly over h bits
#pragma unroll
    for (int k = 0; k < 8; k++) {
        float t1 = __shfl(acc[k], lane + 16);
        float t2 = __shfl(acc[k], lane + 32);
        acc[k] += t1 + t2;
        acc[k] += __shfl_xor(acc[k], 4);
        acc[k] += __shfl_xor(acc[k], 8);
    }
    if (lane < 4) {
        int q = lane;
        float hv[8];
        float m = -1e30f;
#pragma unroll
        for (int t = 0; t < 8; t++) {
            hv[t] = acc[t] * (1.f / 12.f) + ldf(b2, (size_t)(8 * q + t), isF32);
            m = fmaxf(m, hv[t]);
        }
        m = fmaxf(m, __shfl_xor(m, 1));
        m = fmaxf(m, __shfl_xor(m, 2));
        float s = 0.f;
#pragma unroll
        for (int t = 0; t < 8; t++) s += expf(hv[t] - m);
        s += __shfl_xor(s, 1);
        s += __shfl_xor(s, 2);
        float ls = m + logf(s);
        float4* o0 = (float4*)(out + (size_t)node * 32 + 8 * q);
        float4* l0 = (float4*)(out + (size_t)N_NODES * 32 + (size_t)node * 32 + 8 * q);
        o0[0] = make_float4(hv[0], hv[1], hv[2], hv[3]);
        o0[1] = make_float4(hv[4], hv[5], hv[6], hv[7]);
        l0[0] = make_float4(hv[0] - ls, hv[1] - ls, hv[2] - ls, hv[3] - ls);
        l0[1] = make_float4(hv[4] - ls, hv[5] - ls, hv[6] - ls, hv[7] - ls);
    }
}

extern "C" void kernel_launch(void* const* d_in, const int* in_sizes, int n_in,
                              void* d_out, int out_size, void* d_ws, size_t ws_size,
                              hipStream_t stream) {
    const void* x        = d_in[0];
    const void* ei       = d_in[1];
    const void* ea       = d_in[2];
    const void* W1       = d_in[3];
    const void* att_src1 = d_in[4];
    const void* att_dst1 = d_in[5];
    const void* We1      = d_in[6];
    const void* att_e1   = d_in[7];
    const void* b1       = d_in[8];
    const void* W2       = d_in[9];
    const void* att_src2 = d_in[10];
    const void* att_dst2 = d_in[11];
    const void* b2       = d_in[12];
    float* out = (float*)d_out;

    char* ws = (char*)d_ws;
    size_t off = 0;
    auto alloc = [&](size_t bytes) -> void* {
        void* p = ws + off;
        off = (off + bytes + 255) & ~(size_t)255;
        return p;
    };
    int*            flags   = (int*)alloc(16);
    float*          M1      = (float*)alloc((size_t)384 * 4);
    int*            rowptr  = (int*)alloc((size_t)(N_NODES + 1) * 4);
    int*            cnt     = (int*)alloc((size_t)N_NODES * 4);
    int*            wofs    = (int*)alloc((size_t)N_NODES * 4);
    int*            incl    = (int*)alloc((size_t)N_NODES * 4);
    int*            bsum    = (int*)alloc((size_t)NBLK * 4);
    int*            boff    = (int*)alloc((size_t)NBLK * 4);
    float*          a_s     = (float*)alloc((size_t)N_NODES * 12 * 4);
    float*          a_d     = (float*)alloc((size_t)N_NODES * 12 * 4);
    float*          exl     = (float*)alloc((size_t)N_NODES * 12 * 4);
    float*          rden    = (float*)alloc((size_t)N_NODES * 12 * 4);
    int2*           pairs   = (int2*)alloc((size_t)N_EDGES * 8);
    unsigned short* alpha_e = (unsigned short*)alloc((size_t)N_EDGES * 12 * 2);
    unsigned short* hx      = (unsigned short*)alloc((size_t)N_NODES * HC * 2);
    // h1 aliases ae_edge: ae_edge dead after softmax1, h1 born in agg1 (after).
    unsigned short* h1      = (unsigned short*)alloc((size_t)N_NODES * HC * 2);
    unsigned short* ae_edge = h1;
    unsigned short* Wt1     = (unsigned short*)alloc((size_t)HCX * 256 * 2);
    unsigned short* Wt2     = (unsigned short*)alloc((size_t)HCX * 384 * 2);

    hipMemsetAsync(cnt, 0, (size_t)N_NODES * 4, stream);
    detect_kernel<<<1, 256, 0, stream>>>((const unsigned short*)x, (const unsigned int*)ei, flags);
    prep_kernel<<<(384 + HCX * 256 + HCX * 384 + 255) / 256, 256, 0, stream>>>(
        We1, att_e1, W1, W2, att_src1, att_dst1, att_src2, att_dst2, flags, M1, Wt1, Wt2);
    hist_kernel<<<(N_EDGES + 255) / 256, 256, 0, stream>>>(ei, flags, cnt);
    blockscan_kernel<<<NBLK, 256, 0, stream>>>(cnt, incl, bsum);
    bscan_kernel<<<1, 128, 0, stream>>>(bsum, boff);
    finalize_kernel<<<NBLK, 256, 0, stream>>>(incl, boff, cnt, rowptr, wofs);
    scatter_kernel<<<(N_EDGES + 255) / 256, 256, 0, stream>>>(ei, flags, wofs, pairs);
    ae_kernel<<<(N_EDGES + 255) / 256, 256, 0, stream>>>(ea, flags, M1, pairs, ae_edge);
    // layer 1 (att logits via folded B columns)
    gemm_mfma<<<(N_NODES + 63) / 64, 512, 0, stream>>>(x, Wt1, flags, 1, hx, a_s, a_d,
                                                       N_NODES, NFEAT);
    softmax_kernel<<<(N_NODES * 12 + 255) / 256, 256, 0, stream>>>(a_s, a_d, rowptr, pairs,
                                                                   ae_edge, alpha_e, exl, rden, 1);
    agg1_kernel<<<(N_NODES + 3) / 4, 256, 0, stream>>>(hx, alpha_e, exl, rden, rowptr, pairs,
                                                       b1, flags, h1);
    // layer 2 (att logits via folded B columns)
    gemm_mfma<<<(N_NODES + 63) / 64, 512, 0, stream>>>(h1, Wt2, flags, 0, hx, a_s, a_d,
                                                       N_NODES, HC);
    softmax_kernel<<<(N_NODES * 12 + 255) / 256, 256, 0, stream>>>(a_s, a_d, rowptr, pairs,
                                                                   ae_edge, alpha_e, exl, rden, 0);
    agg2_kernel<<<(N_NODES + 3) / 4, 256, 0, stream>>>(hx, alpha_e, exl, rden, rowptr, pairs,
                                                       b2, flags, out);
}